// Round 1
// baseline (590.142 us; speedup 1.0000x reference)
//
#include <hip/hip_runtime.h>

#define DH 128

static constexpr float TEMP_ = 10.0f;
static constexpr float LN_EPS_ = 1e-5f;

// ---------------- bf16 helpers ----------------
__device__ __forceinline__ unsigned short f2bf(float f) {
  union { float f; unsigned int i; } v; v.f = f;
  unsigned int b = v.i + 0x7FFFu + ((v.i >> 16) & 1u);   // RNE
  return (unsigned short)(b >> 16);
}
__device__ __forceinline__ void dec2(unsigned int u, float& lo, float& hi) {
  union { unsigned int i; float f; } a, b;
  a.i = u << 16; b.i = u & 0xFFFF0000u;
  lo = a.f; hi = b.f;
}
__device__ __forceinline__ void dec8(uint4 u, float* o) {
  dec2(u.x, o[0], o[1]); dec2(u.y, o[2], o[3]);
  dec2(u.z, o[4], o[5]); dec2(u.w, o[6], o[7]);
}
__device__ __forceinline__ unsigned int pack2(float lo, float hi) {
  return (unsigned int)f2bf(lo) | ((unsigned int)f2bf(hi) << 16);
}

__device__ __forceinline__ float grp_sum16(float v) {
  #pragma unroll
  for (int o = 8; o > 0; o >>= 1) v += __shfl_down(v, o, 16);
  return __shfl(v, 0, 16);
}

// 256-thread block reduce; s4 = 4-float LDS scratch. Returns to all threads.
__device__ __forceinline__ float blkred(float v, bool mx, float* s4) {
  const int t = threadIdx.x;
  #pragma unroll
  for (int o = 32; o > 0; o >>= 1) {
    float u = __shfl_down(v, o, 64);
    v = mx ? fmaxf(v, u) : v + u;
  }
  __syncthreads();
  if ((t & 63) == 0) s4[t >> 6] = v;
  __syncthreads();
  float r = mx ? fmaxf(fmaxf(s4[0], s4[1]), fmaxf(s4[2], s4[3]))
               : (s4[0] + s4[1]) + (s4[2] + s4[3]);
  __syncthreads();
  return r;
}

// ---------------- device-scope grid barrier ----------------
// bar[0] = arrive counter, bar[1] = generation. Zeroed by host memset.
// Relaxed spin (no per-poll cache invalidate); one agent acquire fence on exit,
// one agent release fence on entry (flushes this XCD's L2 — required because
// per-XCD L2s are not cross-coherent).
__device__ __forceinline__ void gsync(unsigned int* bar) {
  __syncthreads();
  if (threadIdx.x == 0) {
    unsigned int* cnt = bar;
    unsigned int* gen = bar + 1;
    __builtin_amdgcn_fence(__ATOMIC_RELEASE, "agent");
    unsigned int g = __hip_atomic_load(gen, __ATOMIC_RELAXED, __HIP_MEMORY_SCOPE_AGENT);
    unsigned int a = __hip_atomic_fetch_add(cnt, 1u, __ATOMIC_RELAXED, __HIP_MEMORY_SCOPE_AGENT);
    if (a == gridDim.x - 1u) {
      __hip_atomic_store(cnt, 0u, __ATOMIC_RELAXED, __HIP_MEMORY_SCOPE_AGENT);
      __hip_atomic_fetch_add(gen, 1u, __ATOMIC_RELEASE, __HIP_MEMORY_SCOPE_AGENT);
    } else {
      while (__hip_atomic_load(gen, __ATOMIC_RELAXED, __HIP_MEMORY_SCOPE_AGENT) == g)
        __builtin_amdgcn_s_sleep(4);
    }
    __builtin_amdgcn_fence(__ATOMIC_ACQUIRE, "agent");
  }
  __syncthreads();
}

struct MP {
  const float* x;
  const int*   ei;
  const float *W1, *b1, *W2, *b2, *Wout, *bout, *gam, *bet;
  float* out;
  float *G, *Ax, *sq, *En, *dinv, *dego, *gmax;
  unsigned short *Hb, *Gb;
  int *cnt_d, *cnt_s, *off_d, *off_s, *bsum, *idx_d, *idx_s;
  unsigned int* bar;
  int N, E;
};

// ------- conv aggregate (prescaled rows): 16 lanes/node, uint4/lane --------
__device__ __forceinline__ void conv_agg_phase(const MP& p, const float* b) {
  const int t = threadIdx.x;
  const int NT = p.N >> 4;
  const uint4* Hv = (const uint4*)p.Hb;
  for (int tile = blockIdx.x; tile < NT; tile += gridDim.x) {
    const int lane = t & 15;
    const int i = tile * 16 + (t >> 4);
    const float di = p.dinv[i];
    float acc[8];
    dec8(Hv[i * 16 + lane], acc);              // self row (already dinv-scaled)
    int o = p.off_d[i];
    const int oe = p.off_d[i + 1];
    for (; o + 8 <= oe; o += 8) {
      int s[8]; uint4 r[8];
      #pragma unroll
      for (int j = 0; j < 8; ++j) s[j] = p.idx_d[o + j];
      #pragma unroll
      for (int j = 0; j < 8; ++j) r[j] = Hv[s[j] * 16 + lane];
      #pragma unroll
      for (int j = 0; j < 8; ++j) {
        float t8[8]; dec8(r[j], t8);
        #pragma unroll
        for (int k = 0; k < 8; ++k) acc[k] += t8[k];
      }
    }
    for (; o < oe; ++o) {
      int s = p.idx_d[o];
      float t8[8]; dec8(Hv[s * 16 + lane], t8);
      #pragma unroll
      for (int k = 0; k < 8; ++k) acc[k] += t8[k];
    }
    const float4 b0 = ((const float4*)b)[lane * 2];
    const float4 b1 = ((const float4*)b)[lane * 2 + 1];
    float gi[8];
    gi[0] = fmaf(di, acc[0], b0.x); gi[1] = fmaf(di, acc[1], b0.y);
    gi[2] = fmaf(di, acc[2], b0.z); gi[3] = fmaf(di, acc[3], b0.w);
    gi[4] = fmaf(di, acc[4], b1.x); gi[5] = fmaf(di, acc[5], b1.y);
    gi[6] = fmaf(di, acc[6], b1.z); gi[7] = fmaf(di, acc[7], b1.w);
    ((float4*)p.G)[i * 32 + lane * 2]     = make_float4(gi[0], gi[1], gi[2], gi[3]);
    ((float4*)p.G)[i * 32 + lane * 2 + 1] = make_float4(gi[4], gi[5], gi[6], gi[7]);
    uint4 gp;
    gp.x = pack2(gi[0], gi[1]); gp.y = pack2(gi[2], gi[3]);
    gp.z = pack2(gi[4], gi[5]); gp.w = pack2(gi[6], gi[7]);
    ((uint4*)p.Gb)[i * 16 + lane] = gp;
    float s2 = 0.f;
    #pragma unroll
    for (int k = 0; k < 8; ++k) s2 += gi[k] * gi[k];
    s2 = grp_sum16(s2);
    if (lane == 0) p.sq[i] = s2;
  }
}

// ------- Ax = A@G (CSR_src), Asq, En; fold global max(En) via atomicMax ----
__device__ __forceinline__ void ax_en_phase(const MP& p, float* gmax) {
  const int t = threadIdx.x;
  const int NT = p.N >> 4;
  const uint4* Gv = (const uint4*)p.Gb;
  for (int tile = blockIdx.x; tile < NT; tile += gridDim.x) {
    const int lane = t & 15;
    const int i = tile * 16 + (t >> 4);
    float axf[8];
    #pragma unroll
    for (int k = 0; k < 8; ++k) axf[k] = 0.f;
    float asq = 0.f;
    int o = p.off_s[i];
    const int oe = p.off_s[i + 1];
    for (; o + 8 <= oe; o += 8) {
      int s[8]; float qv[8]; uint4 r[8];
      #pragma unroll
      for (int j = 0; j < 8; ++j) s[j] = p.idx_s[o + j];
      #pragma unroll
      for (int j = 0; j < 8; ++j) { r[j] = Gv[s[j] * 16 + lane]; qv[j] = p.sq[s[j]]; }
      #pragma unroll
      for (int j = 0; j < 8; ++j) {
        float t8[8]; dec8(r[j], t8);
        asq += qv[j];
        #pragma unroll
        for (int k = 0; k < 8; ++k) axf[k] += t8[k];
      }
    }
    for (; o < oe; ++o) {
      int s = p.idx_s[o];
      float t8[8]; dec8(Gv[s * 16 + lane], t8);
      asq += p.sq[s];
      #pragma unroll
      for (int k = 0; k < 8; ++k) axf[k] += t8[k];
    }
    ((float4*)p.Ax)[i * 32 + lane * 2]     = make_float4(axf[0], axf[1], axf[2], axf[3]);
    ((float4*)p.Ax)[i * 32 + lane * 2 + 1] = make_float4(axf[4], axf[5], axf[6], axf[7]);
    const float4 g0 = ((const float4*)p.G)[i * 32 + lane * 2];
    const float4 g1 = ((const float4*)p.G)[i * 32 + lane * 2 + 1];
    float dot = g0.x * axf[0] + g0.y * axf[1] + g0.z * axf[2] + g0.w * axf[3]
              + g1.x * axf[4] + g1.y * axf[5] + g1.z * axf[6] + g1.w * axf[7];
    dot = grp_sum16(dot);
    if (lane == 0) {
      float en = 0.5f * (p.dego[i] * p.sq[i] + asq - 2.f * dot);
      p.En[i] = en;
      atomicMax((int*)gmax, __float_as_int(en));   // En >= 0: int-max == float-max
    }
  }
}

// ------- softmax stats + combine + relu + LN + GEMM tile -------------------
template <int DOUT>
__device__ __forceinline__ void combine_gemm_phase(const MP& p, const float* W,
                                                   float m, float* Ws, float* xs,
                                                   float* s4) {
  const int t = threadIdx.x;
  const int n = p.N;
  // ---- softmax statistics (global max m already known) ----
  const float invden = -1.0f / ((m + 1e-12f) * TEMP_);
  float se = 0.f, sl = 0.f;
  for (int k = t; k < n; k += 256) {
    float li = p.En[k] * invden;
    float e = __expf(li);
    se += e; sl += e * li;
  }
  se = blkred(se, false, s4);
  sl = blkred(sl, false, s4);
  const float logZ = __logf(se);
  const float S = logZ - sl / se;
  const float cmul = (1.0f / se) * (1.0f / TEMP_);
  const float cadd = S - logZ;

  const uint4* Gv = (const uint4*)p.Gb;
  const int NT = n >> 4;
  for (int tile = blockIdx.x; tile < NT; tile += gridDim.x) {
    __syncthreads();                 // protect xs/Ws reuse across tile iterations
    const int lane = t & 15;
    const int i = tile * 16 + (t >> 4);
    const float4 g0 = ((const float4*)p.G)[i * 32 + lane * 2];
    const float4 g1 = ((const float4*)p.G)[i * 32 + lane * 2 + 1];
    const float gi[8] = { g0.x, g0.y, g0.z, g0.w, g1.x, g1.y, g1.z, g1.w };
    float tf[8];
    #pragma unroll
    for (int k = 0; k < 8; ++k) tf[k] = 0.f;
    float atc = 0.f;
    int o = p.off_d[i];
    const int oe = p.off_d[i + 1];
    for (; o + 8 <= oe; o += 8) {
      int s[8]; float ev[8]; uint4 r[8];
      #pragma unroll
      for (int j = 0; j < 8; ++j) s[j] = p.idx_d[o + j];
      #pragma unroll
      for (int j = 0; j < 8; ++j) { r[j] = Gv[s[j] * 16 + lane]; ev[j] = p.En[s[j]]; }
      #pragma unroll
      for (int j = 0; j < 8; ++j) {
        float ls = ev[j] * invden;
        float cs = __expf(ls) * cmul * (ls + cadd);
        atc += cs;
        float t8[8]; dec8(r[j], t8);
        #pragma unroll
        for (int k = 0; k < 8; ++k) tf[k] = fmaf(cs, t8[k], tf[k]);
      }
    }
    for (; o < oe; ++o) {
      int s = p.idx_d[o];
      float ls = p.En[s] * invden;
      float cs = __expf(ls) * cmul * (ls + cadd);
      atc += cs;
      float t8[8]; dec8(Gv[s * 16 + lane], t8);
      #pragma unroll
      for (int k = 0; k < 8; ++k) tf[k] = fmaf(cs, t8[k], tf[k]);
    }
    const float li_i = p.En[i] * invden;
    const float ci = __expf(li_i) * cmul * (li_i + cadd);
    const float dg = p.dego[i];
    const float4 a0 = ((const float4*)p.Ax)[i * 32 + lane * 2];
    const float4 a1 = ((const float4*)p.Ax)[i * 32 + lane * 2 + 1];
    const float axi[8] = { a0.x, a0.y, a0.z, a0.w, a1.x, a1.y, a1.z, a1.w };
    float v[8];
    float ssum = 0.f;
    #pragma unroll
    for (int k = 0; k < 8; ++k) {
      v[k] = fmaxf(gi[k] + ci * (dg * gi[k] - axi[k]) + atc * gi[k] - tf[k], 0.f);
      ssum += v[k];
    }
    float mu = grp_sum16(ssum) * (1.f / 128.f);
    float vsum = 0.f;
    #pragma unroll
    for (int k = 0; k < 8; ++k) {
      v[k] -= mu;
      vsum += v[k] * v[k];
    }
    float var = grp_sum16(vsum) * (1.f / 128.f);
    float rs = rsqrtf(var + LN_EPS_);
    const float4 ga0 = ((const float4*)p.gam)[lane * 2];
    const float4 ga1 = ((const float4*)p.gam)[lane * 2 + 1];
    const float4 be0 = ((const float4*)p.bet)[lane * 2];
    const float4 be1 = ((const float4*)p.bet)[lane * 2 + 1];
    float4 o0, o1;
    o0.x = fmaf(v[0] * rs, ga0.x, be0.x); o0.y = fmaf(v[1] * rs, ga0.y, be0.y);
    o0.z = fmaf(v[2] * rs, ga0.z, be0.z); o0.w = fmaf(v[3] * rs, ga0.w, be0.w);
    o1.x = fmaf(v[4] * rs, ga1.x, be1.x); o1.y = fmaf(v[5] * rs, ga1.y, be1.y);
    o1.z = fmaf(v[6] * rs, ga1.z, be1.z); o1.w = fmaf(v[7] * rs, ga1.w, be1.w);

    // ---- stage LN rows to LDS, then GEMM this 16-row tile ----
    float* xrow = xs + (t >> 4) * 128 + lane * 8;
    ((float4*)xrow)[0] = o0;
    ((float4*)xrow)[1] = o1;

    const int row0 = tile * 16;
    constexpr int RPT = (16 * DOUT) / 256;
    const int c = t % DOUT;
    const int rg = t / DOUT;
    float acc[RPT];
    #pragma unroll
    for (int r = 0; r < RPT; ++r) acc[r] = 0.f;
    for (int kt = 0; kt < 2; ++kt) {
      if (kt) __syncthreads();
      for (int idx = t; idx < 64 * DOUT; idx += 256) Ws[idx] = W[kt * 64 * DOUT + idx];
      __syncthreads();
      for (int k = 0; k < 64; ++k) {
        float wv = Ws[k * DOUT + c];
        #pragma unroll
        for (int r = 0; r < RPT; ++r)
          acc[r] += xs[(rg * RPT + r) * 128 + kt * 64 + k] * wv;
      }
    }
    #pragma unroll
    for (int r = 0; r < RPT; ++r) {
      const int row = row0 + rg * RPT + r;
      p.Hb[row * DOUT + c] = f2bf(p.dinv[row] * acc[r]);   // prescaled output
    }
  }
}

// ------- final conv aggregate (prescaled, DOUT=64): 8 lanes/node -----------
__device__ __forceinline__ void final_agg_phase(const MP& p) {
  const int t = threadIdx.x;
  const int NT32 = p.N >> 5;
  const uint4* Hv = (const uint4*)p.Hb;
  for (int tile = blockIdx.x; tile < NT32; tile += gridDim.x) {
    const int lane = t & 7;
    const int i = tile * 32 + (t >> 3);
    const float di = p.dinv[i];
    float acc[8];
    dec8(Hv[i * 8 + lane], acc);
    int o = p.off_d[i];
    const int oe = p.off_d[i + 1];
    for (; o + 8 <= oe; o += 8) {
      int s[8]; uint4 r[8];
      #pragma unroll
      for (int j = 0; j < 8; ++j) s[j] = p.idx_d[o + j];
      #pragma unroll
      for (int j = 0; j < 8; ++j) r[j] = Hv[s[j] * 8 + lane];
      #pragma unroll
      for (int j = 0; j < 8; ++j) {
        float t8[8]; dec8(r[j], t8);
        #pragma unroll
        for (int k = 0; k < 8; ++k) acc[k] += t8[k];
      }
    }
    for (; o < oe; ++o) {
      int s = p.idx_d[o];
      float t8[8]; dec8(Hv[s * 8 + lane], t8);
      #pragma unroll
      for (int k = 0; k < 8; ++k) acc[k] += t8[k];
    }
    const float4 b0 = ((const float4*)p.bout)[lane * 2];
    const float4 b1 = ((const float4*)p.bout)[lane * 2 + 1];
    float4 r0, r1;
    r0.x = fmaf(di, acc[0], b0.x); r0.y = fmaf(di, acc[1], b0.y);
    r0.z = fmaf(di, acc[2], b0.z); r0.w = fmaf(di, acc[3], b0.w);
    r1.x = fmaf(di, acc[4], b1.x); r1.y = fmaf(di, acc[5], b1.y);
    r1.z = fmaf(di, acc[6], b1.z); r1.w = fmaf(di, acc[7], b1.w);
    ((float4*)p.out)[i * 16 + lane * 2]     = r0;
    ((float4*)p.out)[i * 16 + lane * 2 + 1] = r1;
  }
}

// ======================= fused persistent kernel ===========================
__global__ __launch_bounds__(256, 2) void k_mega(MP p) {
  __shared__ float Ws[64 * DH];   // 32 KiB
  __shared__ float xs[16 * DH];   //  8 KiB
  __shared__ float s4[4];
  __shared__ int ws4[4];
  const int t = threadIdx.x;
  const int nb = gridDim.x;
  const int N = p.N, E = p.E;
  const int NT = N >> 4;

  // ---- P1: degree histogram (cnt_* zeroed by host memset) ----
  for (int e = blockIdx.x * 256 + t; e < E; e += nb * 256) {
    atomicAdd(&p.cnt_s[p.ei[e]], 1);
    atomicAdd(&p.cnt_d[p.ei[E + e]], 1);
  }
  gsync(p.bar);

  // ---- P2: hierarchical scan A (blocks 0..63: 32 per direction) ----
  if (blockIdx.x < 64) {
    const int dir = blockIdx.x >> 5, blk = blockIdx.x & 31;
    const int* cnt = dir ? p.cnt_s : p.cnt_d;
    int* off = dir ? p.off_s : p.off_d;
    const int NPB = (N + 31) >> 5;
    const int i = blk * NPB + t;
    const bool valid = (t < NPB) && (i < N);
    int tot = valid ? cnt[i] : 0;
    const int lane = t & 63, w = t >> 6;
    int v = tot;
    #pragma unroll
    for (int o = 1; o < 64; o <<= 1) {
      int u = __shfl_up(v, o, 64);
      if (lane >= o) v += u;
    }
    if (lane == 63) ws4[w] = v;
    __syncthreads();
    int wbase = 0;
    #pragma unroll
    for (int k = 0; k < 4; ++k) wbase += (k < w) ? ws4[k] : 0;
    const int excl = wbase + v - tot;
    if (valid) {
      off[i] = excl;                          // temp: block-local prefix
      if (dir == 0) p.dinv[i] = rsqrtf((float)tot + 1.0f);
      else          p.dego[i] = (float)tot;
    }
    if (t == 0) {
      int bt = 0;
      #pragma unroll
      for (int k = 0; k < 4; ++k) bt += ws4[k];
      p.bsum[dir * 32 + blk] = bt;
    }
  }
  gsync(p.bar);

  // ---- P3: scan B — finalize offsets, zero cnt (fill cursors) ----
  if (blockIdx.x < 64) {
    const int dir = blockIdx.x >> 5, blk = blockIdx.x & 31;
    int* cnt = dir ? p.cnt_s : p.cnt_d;
    int* off = dir ? p.off_s : p.off_d;
    if (t == 0) {
      int s = 0;
      for (int k = 0; k < blk; ++k) s += p.bsum[dir * 32 + k];
      ws4[0] = s;
    }
    __syncthreads();
    const int bbase = ws4[0];
    const int NPB = (N + 31) >> 5;
    const int i = blk * NPB + t;
    if (t < NPB && i < N) {
      off[i] = bbase + off[i];
      cnt[i] = 0;
    }
    if (t == 1 && blk == 31) {
      int s = 0;
      for (int k = 0; k < 32; ++k) s += p.bsum[dir * 32 + k];
      off[N] = s;
    }
  }
  gsync(p.bar);

  // ---- P4: layer-1 GEMM with dinv prescale + CSR fill ----
  for (int tile = blockIdx.x; tile < NT; tile += nb) {
    __syncthreads();
    const int row0 = tile * 16;
    const float4* xg = (const float4*)(p.x + row0 * DH);
    float4* xs4 = (float4*)xs;
    xs4[t] = xg[t];
    xs4[t + 256] = xg[t + 256];
    const int c = t & 127, rg = t >> 7;   // RPT = 8
    float acc[8];
    #pragma unroll
    for (int r = 0; r < 8; ++r) acc[r] = 0.f;
    for (int kt = 0; kt < 2; ++kt) {
      __syncthreads();
      for (int i2 = t; i2 < 64 * DH; i2 += 256) Ws[i2] = p.W1[kt * 64 * DH + i2];
      __syncthreads();
      for (int k = 0; k < 64; ++k) {
        float wv = Ws[k * DH + c];
        #pragma unroll
        for (int r = 0; r < 8; ++r)
          acc[r] += xs[(rg * 8 + r) * DH + kt * 64 + k] * wv;
      }
    }
    #pragma unroll
    for (int r = 0; r < 8; ++r) {
      const int row = row0 + rg * 8 + r;
      p.Hb[row * DH + c] = f2bf(p.dinv[row] * acc[r]);
    }
  }
  for (int e = blockIdx.x * 256 + t; e < E; e += nb * 256) {
    int s = p.ei[e], d = p.ei[E + e];
    int pp = atomicAdd(&p.cnt_d[d], 1);
    p.idx_d[p.off_d[d] + pp] = s;
    int q = atomicAdd(&p.cnt_s[s], 1);
    p.idx_s[p.off_s[s] + q] = d;
  }
  gsync(p.bar);

  // ---- layer 0 ----
  conv_agg_phase(p, p.b1);
  gsync(p.bar);
  ax_en_phase(p, p.gmax);
  gsync(p.bar);
  combine_gemm_phase<DH>(p, p.W2, p.gmax[0], Ws, xs, s4);
  gsync(p.bar);

  // ---- layer 1 ----
  conv_agg_phase(p, p.b2);
  gsync(p.bar);
  ax_en_phase(p, p.gmax + 1);
  gsync(p.bar);
  combine_gemm_phase<64>(p, p.Wout, p.gmax[1], Ws, xs, s4);
  gsync(p.bar);

  // ---- final aggregate ----
  final_agg_phase(p);
}

extern "C" void kernel_launch(void* const* d_in, const int* in_sizes, int n_in,
                              void* d_out, int out_size, void* d_ws, size_t ws_size,
                              hipStream_t stream) {
  MP p;
  p.x    = (const float*)d_in[0];
  p.ei   = (const int*)d_in[1];
  p.W1   = (const float*)d_in[2];
  p.b1   = (const float*)d_in[3];
  p.W2   = (const float*)d_in[4];
  p.b2   = (const float*)d_in[5];
  p.Wout = (const float*)d_in[6];
  p.bout = (const float*)d_in[7];
  p.gam  = (const float*)d_in[8];
  p.bet  = (const float*)d_in[9];
  p.out  = (float*)d_out;

  const int N = in_sizes[0] / DH;   // 8000
  const int E = in_sizes[1] / 2;    // 256000
  p.N = N; p.E = E;

  float* ws = (float*)d_ws;
  p.G  = ws;   ws += N * DH;
  p.Ax = ws;   ws += N * DH;
  p.sq = ws;   ws += N;
  p.En = ws;   ws += N;
  p.dinv = ws; ws += N;
  p.dego = ws; ws += N;
  p.Hb = (unsigned short*)ws; ws += N * DH / 2;   // bf16 N x 128
  p.Gb = (unsigned short*)ws; ws += N * DH / 2;   // bf16 N x 128
  p.cnt_d = (int*)ws; ws += N;
  p.cnt_s = (int*)ws; ws += N;
  p.gmax  = (float*)ws; ws += 2;                  // [0]=layer0 max, [1]=layer1 max
  p.bar   = (unsigned int*)ws; ws += 2;           // grid barrier {cnt, gen}
  p.off_d = (int*)ws; ws += N + 4;
  p.off_s = (int*)ws; ws += N + 4;
  p.bsum  = (int*)ws; ws += 64;
  p.idx_d = (int*)ws; ws += E;
  p.idx_s = (int*)ws; ws += E;

  // Size grid so all blocks are co-resident (manual grid barrier => mandatory).
  // LDS 40.1 KiB/block + __launch_bounds__(256,2) => expect 2 blocks/CU -> 512.
  int mb = 0;
  if (hipOccupancyMaxActiveBlocksPerMultiprocessor(&mb, k_mega, 256, 0) != hipSuccess)
    mb = 0;
  int nb = (mb > 0) ? mb * 256 : 64;   // 256 CUs on MI355X; 64 = safe fallback
  if (nb > 1024) nb = 1024;

  // zero cnt_d, cnt_s, gmax[2], bar[2] (contiguous)
  hipMemsetAsync(p.cnt_d, 0, (size_t)(2 * N + 4) * sizeof(int), stream);
  k_mega<<<nb, 256, 0, stream>>>(p);
}

// Round 2
// 357.809 us; speedup vs baseline: 1.6493x; 1.6493x over previous
//
#include <hip/hip_runtime.h>

#define DH 128

static constexpr float TEMP_ = 10.0f;
static constexpr float LN_EPS_ = 1e-5f;

// ---------------- bf16 helpers ----------------
__device__ __forceinline__ unsigned short f2bf(float f) {
  union { float f; unsigned int i; } v; v.f = f;
  unsigned int b = v.i + 0x7FFFu + ((v.i >> 16) & 1u);   // RNE
  return (unsigned short)(b >> 16);
}
__device__ __forceinline__ void dec2(unsigned int u, float& lo, float& hi) {
  union { unsigned int i; float f; } a, b;
  a.i = u << 16; b.i = u & 0xFFFF0000u;
  lo = a.f; hi = b.f;
}
__device__ __forceinline__ void dec8(uint4 u, float* o) {
  dec2(u.x, o[0], o[1]); dec2(u.y, o[2], o[3]);
  dec2(u.z, o[4], o[5]); dec2(u.w, o[6], o[7]);
}
__device__ __forceinline__ unsigned int pack2(float lo, float hi) {
  return (unsigned int)f2bf(lo) | ((unsigned int)f2bf(hi) << 16);
}

__device__ __forceinline__ float grp_sum16(float v) {
  #pragma unroll
  for (int o = 8; o > 0; o >>= 1) v += __shfl_down(v, o, 16);
  return __shfl(v, 0, 16);
}

// 256-thread block reduce; s4 = 4-float LDS scratch. Returns to all threads.
__device__ __forceinline__ float blkred(float v, float* s4) {
  const int t = threadIdx.x;
  #pragma unroll
  for (int o = 32; o > 0; o >>= 1) v += __shfl_down(v, o, 64);
  __syncthreads();
  if ((t & 63) == 0) s4[t >> 6] = v;
  __syncthreads();
  float r = (s4[0] + s4[1]) + (s4[2] + s4[3]);
  __syncthreads();
  return r;
}

// ---------------- hierarchical device-scope grid barrier ----------------
// bar layout (u32): cells[64] strided 32 (one per 128B line), root @2048,
// gen @2080 (own line). All counters monotonic -> no reset races.
// Requires gridDim.x % 64 == 0 and all blocks co-resident.
__device__ __forceinline__ void gsync(unsigned int* bar) {
  __syncthreads();
  if (threadIdx.x == 0) {
    unsigned int* root = bar + 2048;
    unsigned int* gen  = bar + 2080;
    __builtin_amdgcn_fence(__ATOMIC_RELEASE, "agent");
    unsigned int g = __hip_atomic_load(gen, __ATOMIC_RELAXED, __HIP_MEMORY_SCOPE_AGENT);
    const unsigned int quota = gridDim.x >> 6;
    unsigned int a = __hip_atomic_fetch_add(bar + (blockIdx.x & 63) * 32, 1u,
                                            __ATOMIC_RELAXED, __HIP_MEMORY_SCOPE_AGENT);
    if (((a + 1u) % quota) == 0u) {
      unsigned int r = __hip_atomic_fetch_add(root, 1u, __ATOMIC_RELAXED,
                                              __HIP_MEMORY_SCOPE_AGENT);
      if (((r + 1u) & 63u) == 0u)
        __hip_atomic_fetch_add(gen, 1u, __ATOMIC_RELAXED, __HIP_MEMORY_SCOPE_AGENT);
    }
    while (__hip_atomic_load(gen, __ATOMIC_RELAXED, __HIP_MEMORY_SCOPE_AGENT) == g)
      __builtin_amdgcn_s_sleep(2);
    __builtin_amdgcn_fence(__ATOMIC_ACQUIRE, "agent");
  }
  __syncthreads();
}

struct MP {
  const float* x;
  const int*   ei;
  const float *W1, *b1, *W2, *b2, *Wout, *bout, *gam, *bet;
  float* out;
  float *G, *Ax, *sq, *En, *dinv, *dego, *gmax;
  unsigned short *Hb, *Gb;
  int *cnt_d, *cnt_s, *off_d, *off_s, *bsum, *idx_d, *idx_s;
  unsigned int* bar;
  int N, E;
};

// ------- conv aggregate (prescaled rows): 16 lanes/node, uint4/lane --------
__device__ __forceinline__ void conv_agg_phase(const MP& p, const float* b) {
  const int t = threadIdx.x;
  const int NT = p.N >> 4;
  const uint4* Hv = (const uint4*)p.Hb;
  for (int tile = blockIdx.x; tile < NT; tile += gridDim.x) {
    const int lane = t & 15;
    const int i = tile * 16 + (t >> 4);
    const float di = p.dinv[i];
    float acc[8];
    dec8(Hv[i * 16 + lane], acc);              // self row (already dinv-scaled)
    int o = p.off_d[i];
    const int oe = p.off_d[i + 1];
    for (; o + 8 <= oe; o += 8) {
      int s[8]; uint4 r[8];
      #pragma unroll
      for (int j = 0; j < 8; ++j) s[j] = p.idx_d[o + j];
      #pragma unroll
      for (int j = 0; j < 8; ++j) r[j] = Hv[s[j] * 16 + lane];
      #pragma unroll
      for (int j = 0; j < 8; ++j) {
        float t8[8]; dec8(r[j], t8);
        #pragma unroll
        for (int k = 0; k < 8; ++k) acc[k] += t8[k];
      }
    }
    for (; o < oe; ++o) {
      int s = p.idx_d[o];
      float t8[8]; dec8(Hv[s * 16 + lane], t8);
      #pragma unroll
      for (int k = 0; k < 8; ++k) acc[k] += t8[k];
    }
    const float4 b0 = ((const float4*)b)[lane * 2];
    const float4 b1 = ((const float4*)b)[lane * 2 + 1];
    float gi[8];
    gi[0] = fmaf(di, acc[0], b0.x); gi[1] = fmaf(di, acc[1], b0.y);
    gi[2] = fmaf(di, acc[2], b0.z); gi[3] = fmaf(di, acc[3], b0.w);
    gi[4] = fmaf(di, acc[4], b1.x); gi[5] = fmaf(di, acc[5], b1.y);
    gi[6] = fmaf(di, acc[6], b1.z); gi[7] = fmaf(di, acc[7], b1.w);
    ((float4*)p.G)[i * 32 + lane * 2]     = make_float4(gi[0], gi[1], gi[2], gi[3]);
    ((float4*)p.G)[i * 32 + lane * 2 + 1] = make_float4(gi[4], gi[5], gi[6], gi[7]);
    uint4 gp;
    gp.x = pack2(gi[0], gi[1]); gp.y = pack2(gi[2], gi[3]);
    gp.z = pack2(gi[4], gi[5]); gp.w = pack2(gi[6], gi[7]);
    ((uint4*)p.Gb)[i * 16 + lane] = gp;
    float s2 = 0.f;
    #pragma unroll
    for (int k = 0; k < 8; ++k) s2 += gi[k] * gi[k];
    s2 = grp_sum16(s2);
    if (lane == 0) p.sq[i] = s2;
  }
}

// ------- Ax = A@G (CSR_src), Asq, En; fold global max(En) via atomicMax ----
__device__ __forceinline__ void ax_en_phase(const MP& p, float* gmax) {
  const int t = threadIdx.x;
  const int NT = p.N >> 4;
  const uint4* Gv = (const uint4*)p.Gb;
  for (int tile = blockIdx.x; tile < NT; tile += gridDim.x) {
    const int lane = t & 15;
    const int i = tile * 16 + (t >> 4);
    float axf[8];
    #pragma unroll
    for (int k = 0; k < 8; ++k) axf[k] = 0.f;
    float asq = 0.f;
    int o = p.off_s[i];
    const int oe = p.off_s[i + 1];
    for (; o + 8 <= oe; o += 8) {
      int s[8]; float qv[8]; uint4 r[8];
      #pragma unroll
      for (int j = 0; j < 8; ++j) s[j] = p.idx_s[o + j];
      #pragma unroll
      for (int j = 0; j < 8; ++j) { r[j] = Gv[s[j] * 16 + lane]; qv[j] = p.sq[s[j]]; }
      #pragma unroll
      for (int j = 0; j < 8; ++j) {
        float t8[8]; dec8(r[j], t8);
        asq += qv[j];
        #pragma unroll
        for (int k = 0; k < 8; ++k) axf[k] += t8[k];
      }
    }
    for (; o < oe; ++o) {
      int s = p.idx_s[o];
      float t8[8]; dec8(Gv[s * 16 + lane], t8);
      asq += p.sq[s];
      #pragma unroll
      for (int k = 0; k < 8; ++k) axf[k] += t8[k];
    }
    ((float4*)p.Ax)[i * 32 + lane * 2]     = make_float4(axf[0], axf[1], axf[2], axf[3]);
    ((float4*)p.Ax)[i * 32 + lane * 2 + 1] = make_float4(axf[4], axf[5], axf[6], axf[7]);
    const float4 g0 = ((const float4*)p.G)[i * 32 + lane * 2];
    const float4 g1 = ((const float4*)p.G)[i * 32 + lane * 2 + 1];
    float dot = g0.x * axf[0] + g0.y * axf[1] + g0.z * axf[2] + g0.w * axf[3]
              + g1.x * axf[4] + g1.y * axf[5] + g1.z * axf[6] + g1.w * axf[7];
    dot = grp_sum16(dot);
    if (lane == 0) {
      float en = 0.5f * (p.dego[i] * p.sq[i] + asq - 2.f * dot);
      p.En[i] = en;
      atomicMax((int*)gmax, __float_as_int(en));   // En >= 0: int-max == float-max
    }
  }
}

// ------- softmax stats + combine + relu + LN + GEMM tile -------------------
// W is read directly from L2 (per-block reuse is only 2x; dropping the 32KB
// LDS stage doubles occupancy: 2 -> 4 blocks/CU).
template <int DOUT>
__device__ __forceinline__ void combine_gemm_phase(const MP& p, const float* W,
                                                   const float* gmaxp,
                                                   float* xs, float* s4) {
  const int t = threadIdx.x;
  const int n = p.N;
  const float m = gmaxp[0];
  const float invden = -1.0f / ((m + 1e-12f) * TEMP_);
  float se = 0.f, sl = 0.f;
  for (int k = t; k < n; k += 256) {
    float li = p.En[k] * invden;
    float e = __expf(li);
    se += e; sl += e * li;
  }
  se = blkred(se, s4);
  sl = blkred(sl, s4);
  const float logZ = __logf(se);
  const float S = logZ - sl / se;
  const float cmul = (1.0f / se) * (1.0f / TEMP_);
  const float cadd = S - logZ;

  const uint4* Gv = (const uint4*)p.Gb;
  const int NT = n >> 4;
  for (int tile = blockIdx.x; tile < NT; tile += gridDim.x) {
    __syncthreads();                 // protect xs reuse across tile iterations
    const int lane = t & 15;
    const int i = tile * 16 + (t >> 4);
    const float4 g0 = ((const float4*)p.G)[i * 32 + lane * 2];
    const float4 g1 = ((const float4*)p.G)[i * 32 + lane * 2 + 1];
    const float gi[8] = { g0.x, g0.y, g0.z, g0.w, g1.x, g1.y, g1.z, g1.w };
    float tf[8];
    #pragma unroll
    for (int k = 0; k < 8; ++k) tf[k] = 0.f;
    float atc = 0.f;
    int o = p.off_d[i];
    const int oe = p.off_d[i + 1];
    for (; o + 8 <= oe; o += 8) {
      int s[8]; float ev[8]; uint4 r[8];
      #pragma unroll
      for (int j = 0; j < 8; ++j) s[j] = p.idx_d[o + j];
      #pragma unroll
      for (int j = 0; j < 8; ++j) { r[j] = Gv[s[j] * 16 + lane]; ev[j] = p.En[s[j]]; }
      #pragma unroll
      for (int j = 0; j < 8; ++j) {
        float ls = ev[j] * invden;
        float cs = __expf(ls) * cmul * (ls + cadd);
        atc += cs;
        float t8[8]; dec8(r[j], t8);
        #pragma unroll
        for (int k = 0; k < 8; ++k) tf[k] = fmaf(cs, t8[k], tf[k]);
      }
    }
    for (; o < oe; ++o) {
      int s = p.idx_d[o];
      float ls = p.En[s] * invden;
      float cs = __expf(ls) * cmul * (ls + cadd);
      atc += cs;
      float t8[8]; dec8(Gv[s * 16 + lane], t8);
      #pragma unroll
      for (int k = 0; k < 8; ++k) tf[k] = fmaf(cs, t8[k], tf[k]);
    }
    const float li_i = p.En[i] * invden;
    const float ci = __expf(li_i) * cmul * (li_i + cadd);
    const float dg = p.dego[i];
    const float4 a0 = ((const float4*)p.Ax)[i * 32 + lane * 2];
    const float4 a1 = ((const float4*)p.Ax)[i * 32 + lane * 2 + 1];
    const float axi[8] = { a0.x, a0.y, a0.z, a0.w, a1.x, a1.y, a1.z, a1.w };
    float v[8];
    float ssum = 0.f;
    #pragma unroll
    for (int k = 0; k < 8; ++k) {
      v[k] = fmaxf(gi[k] + ci * (dg * gi[k] - axi[k]) + atc * gi[k] - tf[k], 0.f);
      ssum += v[k];
    }
    float mu = grp_sum16(ssum) * (1.f / 128.f);
    float vsum = 0.f;
    #pragma unroll
    for (int k = 0; k < 8; ++k) {
      v[k] -= mu;
      vsum += v[k] * v[k];
    }
    float var = grp_sum16(vsum) * (1.f / 128.f);
    float rs = rsqrtf(var + LN_EPS_);
    const float4 ga0 = ((const float4*)p.gam)[lane * 2];
    const float4 ga1 = ((const float4*)p.gam)[lane * 2 + 1];
    const float4 be0 = ((const float4*)p.bet)[lane * 2];
    const float4 be1 = ((const float4*)p.bet)[lane * 2 + 1];
    float4 o0, o1;
    o0.x = fmaf(v[0] * rs, ga0.x, be0.x); o0.y = fmaf(v[1] * rs, ga0.y, be0.y);
    o0.z = fmaf(v[2] * rs, ga0.z, be0.z); o0.w = fmaf(v[3] * rs, ga0.w, be0.w);
    o1.x = fmaf(v[4] * rs, ga1.x, be1.x); o1.y = fmaf(v[5] * rs, ga1.y, be1.y);
    o1.z = fmaf(v[6] * rs, ga1.z, be1.z); o1.w = fmaf(v[7] * rs, ga1.w, be1.w);

    // ---- stage LN rows to LDS, then GEMM this 16-row tile ----
    float* xrow = xs + (t >> 4) * 128 + lane * 8;
    ((float4*)xrow)[0] = o0;
    ((float4*)xrow)[1] = o1;
    __syncthreads();

    const int row0 = tile * 16;
    constexpr int RPT = (16 * DOUT) / 256;
    const int c = t % DOUT;
    const int rg = t / DOUT;
    float acc[RPT];
    #pragma unroll
    for (int r = 0; r < RPT; ++r) acc[r] = 0.f;
    #pragma unroll
    for (int kt = 0; kt < 2; ++kt) {
      const float* Wp = W + kt * 64 * DOUT + c;
      #pragma unroll 8
      for (int k = 0; k < 64; ++k) {
        float wv = Wp[k * DOUT];
        #pragma unroll
        for (int r = 0; r < RPT; ++r)
          acc[r] += xs[(rg * RPT + r) * 128 + kt * 64 + k] * wv;
      }
    }
    #pragma unroll
    for (int r = 0; r < RPT; ++r) {
      const int row = row0 + rg * RPT + r;
      p.Hb[row * DOUT + c] = f2bf(p.dinv[row] * acc[r]);   // prescaled output
    }
  }
}

// ------- final conv aggregate (prescaled, DOUT=64): 8 lanes/node -----------
__device__ __forceinline__ void final_agg_phase(const MP& p) {
  const int t = threadIdx.x;
  const int NT32 = p.N >> 5;
  const uint4* Hv = (const uint4*)p.Hb;
  for (int tile = blockIdx.x; tile < NT32; tile += gridDim.x) {
    const int lane = t & 7;
    const int i = tile * 32 + (t >> 3);
    const float di = p.dinv[i];
    float acc[8];
    dec8(Hv[i * 8 + lane], acc);
    int o = p.off_d[i];
    const int oe = p.off_d[i + 1];
    for (; o + 8 <= oe; o += 8) {
      int s[8]; uint4 r[8];
      #pragma unroll
      for (int j = 0; j < 8; ++j) s[j] = p.idx_d[o + j];
      #pragma unroll
      for (int j = 0; j < 8; ++j) r[j] = Hv[s[j] * 8 + lane];
      #pragma unroll
      for (int j = 0; j < 8; ++j) {
        float t8[8]; dec8(r[j], t8);
        #pragma unroll
        for (int k = 0; k < 8; ++k) acc[k] += t8[k];
      }
    }
    for (; o < oe; ++o) {
      int s = p.idx_d[o];
      float t8[8]; dec8(Hv[s * 8 + lane], t8);
      #pragma unroll
      for (int k = 0; k < 8; ++k) acc[k] += t8[k];
    }
    const float4 b0 = ((const float4*)p.bout)[lane * 2];
    const float4 b1 = ((const float4*)p.bout)[lane * 2 + 1];
    float4 r0, r1;
    r0.x = fmaf(di, acc[0], b0.x); r0.y = fmaf(di, acc[1], b0.y);
    r0.z = fmaf(di, acc[2], b0.z); r0.w = fmaf(di, acc[3], b0.w);
    r1.x = fmaf(di, acc[4], b1.x); r1.y = fmaf(di, acc[5], b1.y);
    r1.z = fmaf(di, acc[6], b1.z); r1.w = fmaf(di, acc[7], b1.w);
    ((float4*)p.out)[i * 16 + lane * 2]     = r0;
    ((float4*)p.out)[i * 16 + lane * 2 + 1] = r1;
  }
}

// =================== kernel 1: hist + scan + gemm1 + fill ==================
__global__ __launch_bounds__(256, 4) void k_setup(MP p) {
  __shared__ float xs[16 * DH];
  __shared__ int ws4[4];
  const int t = threadIdx.x;
  const int nb = gridDim.x;
  const int N = p.N, E = p.E;

  // ---- P1: degree histogram (cnt_* zeroed by host memset) ----
  for (int e = blockIdx.x * 256 + t; e < E; e += nb * 256) {
    atomicAdd(&p.cnt_s[p.ei[e]], 1);
    atomicAdd(&p.cnt_d[p.ei[E + e]], 1);
  }
  gsync(p.bar);

  // ---- P2: hierarchical scan A (blocks 0..63: 32 per direction) ----
  if (blockIdx.x < 64) {
    const int dir = blockIdx.x >> 5, blk = blockIdx.x & 31;
    const int* cnt = dir ? p.cnt_s : p.cnt_d;
    int* off = dir ? p.off_s : p.off_d;
    const int NPB = (N + 31) >> 5;
    const int i = blk * NPB + t;
    const bool valid = (t < NPB) && (i < N);
    int tot = valid ? cnt[i] : 0;
    const int lane = t & 63, w = t >> 6;
    int v = tot;
    #pragma unroll
    for (int o = 1; o < 64; o <<= 1) {
      int u = __shfl_up(v, o, 64);
      if (lane >= o) v += u;
    }
    if (lane == 63) ws4[w] = v;
    __syncthreads();
    int wbase = 0;
    #pragma unroll
    for (int k = 0; k < 4; ++k) wbase += (k < w) ? ws4[k] : 0;
    const int excl = wbase + v - tot;
    if (valid) {
      off[i] = excl;                          // temp: block-local prefix
      if (dir == 0) p.dinv[i] = rsqrtf((float)tot + 1.0f);
      else          p.dego[i] = (float)tot;
    }
    if (t == 0) {
      int bt = 0;
      #pragma unroll
      for (int k = 0; k < 4; ++k) bt += ws4[k];
      p.bsum[dir * 32 + blk] = bt;
    }
  }
  gsync(p.bar);

  // ---- P3: scan B — finalize offsets, zero cnt (fill cursors) ----
  if (blockIdx.x < 64) {
    const int dir = blockIdx.x >> 5, blk = blockIdx.x & 31;
    int* cnt = dir ? p.cnt_s : p.cnt_d;
    int* off = dir ? p.off_s : p.off_d;
    if (t == 0) {
      int s = 0;
      for (int k = 0; k < blk; ++k) s += p.bsum[dir * 32 + k];
      ws4[0] = s;
    }
    __syncthreads();
    const int bbase = ws4[0];
    const int NPB = (N + 31) >> 5;
    const int i = blk * NPB + t;
    if (t < NPB && i < N) {
      off[i] = bbase + off[i];
      cnt[i] = 0;
    }
    if (t == 1 && blk == 31) {
      int s = 0;
      for (int k = 0; k < 32; ++k) s += p.bsum[dir * 32 + k];
      off[N] = s;
    }
  }
  gsync(p.bar);

  // ---- P4: layer-1 GEMM with dinv prescale (W1 direct from L2) ----
  const int NT = N >> 4;
  for (int tile = blockIdx.x; tile < NT; tile += nb) {
    __syncthreads();
    const int row0 = tile * 16;
    const float4* xg = (const float4*)(p.x + row0 * DH);
    float4* xs4 = (float4*)xs;
    xs4[t] = xg[t];
    xs4[t + 256] = xg[t + 256];
    __syncthreads();
    const int c = t & 127, rg = t >> 7;   // RPT = 8
    float acc[8];
    #pragma unroll
    for (int r = 0; r < 8; ++r) acc[r] = 0.f;
    #pragma unroll
    for (int kt = 0; kt < 2; ++kt) {
      const float* Wp = p.W1 + kt * 64 * DH + c;
      #pragma unroll 8
      for (int k = 0; k < 64; ++k) {
        float wv = Wp[k * DH];
        #pragma unroll
        for (int r = 0; r < 8; ++r)
          acc[r] += xs[(rg * 8 + r) * DH + kt * 64 + k] * wv;
      }
    }
    #pragma unroll
    for (int r = 0; r < 8; ++r) {
      const int row = row0 + rg * 8 + r;
      p.Hb[row * DH + c] = f2bf(p.dinv[row] * acc[r]);
    }
  }
  // ---- CSR fill ----
  for (int e = blockIdx.x * 256 + t; e < E; e += nb * 256) {
    int s = p.ei[e], d = p.ei[E + e];
    int pp = atomicAdd(&p.cnt_d[d], 1);
    p.idx_d[p.off_d[d] + pp] = s;
    int q = atomicAdd(&p.cnt_s[s], 1);
    p.idx_s[p.off_s[s] + q] = d;
  }
}

// =================== kernel 2/3: one GCN+entropy layer =====================
template <int DOUT, bool FINAL>
__global__ __launch_bounds__(256, 4) void k_layer(MP p, const float* bias,
                                                  const float* W, float* gmaxp) {
  __shared__ float xs[16 * DH];
  __shared__ float s4[4];
  conv_agg_phase(p, bias);
  gsync(p.bar);
  ax_en_phase(p, gmaxp);
  gsync(p.bar);
  combine_gemm_phase<DOUT>(p, W, gmaxp, xs, s4);
  if (FINAL) {
    gsync(p.bar);
    final_agg_phase(p);
  }
}

extern "C" void kernel_launch(void* const* d_in, const int* in_sizes, int n_in,
                              void* d_out, int out_size, void* d_ws, size_t ws_size,
                              hipStream_t stream) {
  MP p;
  p.x    = (const float*)d_in[0];
  p.ei   = (const int*)d_in[1];
  p.W1   = (const float*)d_in[2];
  p.b1   = (const float*)d_in[3];
  p.W2   = (const float*)d_in[4];
  p.b2   = (const float*)d_in[5];
  p.Wout = (const float*)d_in[6];
  p.bout = (const float*)d_in[7];
  p.gam  = (const float*)d_in[8];
  p.bet  = (const float*)d_in[9];
  p.out  = (float*)d_out;

  const int N = in_sizes[0] / DH;   // 8000
  const int E = in_sizes[1] / 2;    // 256000
  p.N = N; p.E = E;

  float* ws = (float*)d_ws;
  p.G  = ws;   ws += N * DH;
  p.Ax = ws;   ws += N * DH;
  p.sq = ws;   ws += N;
  p.En = ws;   ws += N;
  p.dinv = ws; ws += N;
  p.dego = ws; ws += N;
  p.Hb = (unsigned short*)ws; ws += N * DH / 2;   // bf16 N x 128
  p.Gb = (unsigned short*)ws; ws += N * DH / 2;   // bf16 N x 128
  p.cnt_d = (int*)ws; ws += N;
  p.cnt_s = (int*)ws; ws += N;
  p.gmax  = (float*)ws; ws += 2;                  // [0]=layer0 max, [1]=layer1 max
  p.bar   = (unsigned int*)ws; ws += 2112;        // 64 cells*32 + root + gen lines
  p.off_d = (int*)ws; ws += N + 4;
  p.off_s = (int*)ws; ws += N + 4;
  p.bsum  = (int*)ws; ws += 64;
  p.idx_d = (int*)ws; ws += E;
  p.idx_s = (int*)ws; ws += E;

  // Same grid for all kernels (barrier quota consistency: counters are
  // monotonic across kernels, so quota = nb/64 must not change).
  int mb1 = 0, mb2 = 0, mb3 = 0;
  (void)hipOccupancyMaxActiveBlocksPerMultiprocessor(&mb1, k_setup, 256, 0);
  (void)hipOccupancyMaxActiveBlocksPerMultiprocessor(&mb2, k_layer<DH, false>, 256, 0);
  (void)hipOccupancyMaxActiveBlocksPerMultiprocessor(&mb3, k_layer<64, true>, 256, 0);
  int mb = mb1;
  if (mb2 < mb) mb = mb2;
  if (mb3 < mb) mb = mb3;
  if (mb <= 0) mb = 2;
  int nb = mb * 256;                // multiple of 64 by construction
  if (nb > 2048) nb = 2048;

  // zero cnt_d, cnt_s, gmax[2], bar[2112] (contiguous)
  hipMemsetAsync(p.cnt_d, 0, (size_t)(2 * N + 2 + 2112) * sizeof(int), stream);
  k_setup<<<nb, 256, 0, stream>>>(p);
  k_layer<DH, false><<<nb, 256, 0, stream>>>(p, p.b1, p.W2, p.gmax);
  k_layer<64, true><<<nb, 256, 0, stream>>>(p, p.b2, p.Wout, p.gmax + 1);
}

// Round 3
// 353.610 us; speedup vs baseline: 1.6689x; 1.0119x over previous
//
#include <hip/hip_runtime.h>

#define DH 128

static constexpr float TEMP_ = 10.0f;
static constexpr float LN_EPS_ = 1e-5f;

// ---------------- bf16 helpers ----------------
__device__ __forceinline__ unsigned short f2bf(float f) {
  union { float f; unsigned int i; } v; v.f = f;
  unsigned int b = v.i + 0x7FFFu + ((v.i >> 16) & 1u);   // RNE
  return (unsigned short)(b >> 16);
}
__device__ __forceinline__ void dec2(unsigned int u, float& lo, float& hi) {
  union { unsigned int i; float f; } a, b;
  a.i = u << 16; b.i = u & 0xFFFF0000u;
  lo = a.f; hi = b.f;
}
__device__ __forceinline__ void dec8(uint4 u, float* o) {
  dec2(u.x, o[0], o[1]); dec2(u.y, o[2], o[3]);
  dec2(u.z, o[4], o[5]); dec2(u.w, o[6], o[7]);
}
__device__ __forceinline__ unsigned int pack2(float lo, float hi) {
  return (unsigned int)f2bf(lo) | ((unsigned int)f2bf(hi) << 16);
}

__device__ __forceinline__ float grp_sum16(float v) {
  #pragma unroll
  for (int o = 8; o > 0; o >>= 1) v += __shfl_down(v, o, 16);
  return __shfl(v, 0, 16);
}

// 256-thread block reduce; s4 = 4-float LDS scratch. Returns to all threads.
__device__ __forceinline__ float blkred(float v, float* s4) {
  const int t = threadIdx.x;
  #pragma unroll
  for (int o = 32; o > 0; o >>= 1) v += __shfl_down(v, o, 64);
  __syncthreads();
  if ((t & 63) == 0) s4[t >> 6] = v;
  __syncthreads();
  float r = (s4[0] + s4[1]) + (s4[2] + s4[3]);
  __syncthreads();
  return r;
}

// ---------------- hierarchical device-scope grid barrier ----------------
// bar layout (u32, all lines 128B apart):
//   cells[64]  @ c*32      : arrival counters (monotonic)
//   root       @ 2048      : cell-completion counter (monotonic)
//   gen        @ 2080      : global generation (monotonic, +1 per barrier)
//   cgen[64]   @ 2112+c*32 : per-cell copy of gen, written by cell leader
// Wait side is two-level: only blocks 0..63 (cell leaders) poll gen; all
// other blocks poll their cell's cgen line. Sleep backoff caps poll traffic
// at ~0.02 loads/cyc/line so idle blocks cannot congest the memory system
// while other blocks are still working a phase.
// Requires gridDim.x % 64 == 0 and all blocks co-resident.
__device__ __forceinline__ void gsync(unsigned int* bar, unsigned int nbar) {
  __syncthreads();
  if (threadIdx.x == 0) {
    unsigned int* root = bar + 2048;
    unsigned int* gen  = bar + 2080;
    unsigned int* cgen = bar + 2112;
    const unsigned int cell = blockIdx.x & 63;
    const unsigned int quota = gridDim.x >> 6;
    __builtin_amdgcn_fence(__ATOMIC_RELEASE, "agent");
    unsigned int a = __hip_atomic_fetch_add(bar + cell * 32, 1u,
                                            __ATOMIC_RELAXED, __HIP_MEMORY_SCOPE_AGENT);
    if (((a + 1u) % quota) == 0u) {
      unsigned int r = __hip_atomic_fetch_add(root, 1u, __ATOMIC_RELAXED,
                                              __HIP_MEMORY_SCOPE_AGENT);
      if (((r + 1u) & 63u) == 0u)
        __hip_atomic_fetch_add(gen, 1u, __ATOMIC_RELAXED, __HIP_MEMORY_SCOPE_AGENT);
    }
    if (blockIdx.x < 64) {
      // cell leader: wait on global gen, then publish to this cell's line
      int tries = 0;
      while (__hip_atomic_load(gen, __ATOMIC_RELAXED, __HIP_MEMORY_SCOPE_AGENT) < nbar) {
        if (tries < 4) { __builtin_amdgcn_s_sleep(1); ++tries; }
        else           __builtin_amdgcn_s_sleep(32);
      }
      __hip_atomic_store(cgen + cell * 32, nbar, __ATOMIC_RELAXED,
                         __HIP_MEMORY_SCOPE_AGENT);
    } else {
      int tries = 0;
      while (__hip_atomic_load(cgen + cell * 32, __ATOMIC_RELAXED,
                               __HIP_MEMORY_SCOPE_AGENT) < nbar) {
        if (tries < 4) { __builtin_amdgcn_s_sleep(1); ++tries; }
        else           __builtin_amdgcn_s_sleep(32);
      }
    }
    __builtin_amdgcn_fence(__ATOMIC_ACQUIRE, "agent");
  }
  __syncthreads();
}

struct MP {
  const float* x;
  const int*   ei;
  const float *W1, *b1, *W2, *b2, *Wout, *bout, *gam, *bet;
  float* out;
  float *G, *Ax, *sq, *En, *dinv, *dego, *gmax;
  unsigned short *Hb, *Gb;
  int *cnt_d, *cnt_s, *off_d, *off_s, *bsum, *idx_d, *idx_s;
  unsigned int* bar;
  int N, E;
};

// ------- conv aggregate (prescaled rows): 16 lanes/node, uint4/lane --------
__device__ __forceinline__ void conv_agg_phase(const MP& p, const float* b) {
  const int t = threadIdx.x;
  const int NT = p.N >> 4;
  const uint4* Hv = (const uint4*)p.Hb;
  for (int tile = blockIdx.x; tile < NT; tile += gridDim.x) {
    const int lane = t & 15;
    const int i = tile * 16 + (t >> 4);
    const float di = p.dinv[i];
    float acc[8];
    dec8(Hv[i * 16 + lane], acc);              // self row (already dinv-scaled)
    int o = p.off_d[i];
    const int oe = p.off_d[i + 1];
    for (; o + 8 <= oe; o += 8) {
      int s[8]; uint4 r[8];
      #pragma unroll
      for (int j = 0; j < 8; ++j) s[j] = p.idx_d[o + j];
      #pragma unroll
      for (int j = 0; j < 8; ++j) r[j] = Hv[s[j] * 16 + lane];
      #pragma unroll
      for (int j = 0; j < 8; ++j) {
        float t8[8]; dec8(r[j], t8);
        #pragma unroll
        for (int k = 0; k < 8; ++k) acc[k] += t8[k];
      }
    }
    for (; o < oe; ++o) {
      int s = p.idx_d[o];
      float t8[8]; dec8(Hv[s * 16 + lane], t8);
      #pragma unroll
      for (int k = 0; k < 8; ++k) acc[k] += t8[k];
    }
    const float4 b0 = ((const float4*)b)[lane * 2];
    const float4 b1 = ((const float4*)b)[lane * 2 + 1];
    float gi[8];
    gi[0] = fmaf(di, acc[0], b0.x); gi[1] = fmaf(di, acc[1], b0.y);
    gi[2] = fmaf(di, acc[2], b0.z); gi[3] = fmaf(di, acc[3], b0.w);
    gi[4] = fmaf(di, acc[4], b1.x); gi[5] = fmaf(di, acc[5], b1.y);
    gi[6] = fmaf(di, acc[6], b1.z); gi[7] = fmaf(di, acc[7], b1.w);
    ((float4*)p.G)[i * 32 + lane * 2]     = make_float4(gi[0], gi[1], gi[2], gi[3]);
    ((float4*)p.G)[i * 32 + lane * 2 + 1] = make_float4(gi[4], gi[5], gi[6], gi[7]);
    uint4 gp;
    gp.x = pack2(gi[0], gi[1]); gp.y = pack2(gi[2], gi[3]);
    gp.z = pack2(gi[4], gi[5]); gp.w = pack2(gi[6], gi[7]);
    ((uint4*)p.Gb)[i * 16 + lane] = gp;
    float s2 = 0.f;
    #pragma unroll
    for (int k = 0; k < 8; ++k) s2 += gi[k] * gi[k];
    s2 = grp_sum16(s2);
    if (lane == 0) p.sq[i] = s2;
  }
}

// ------- Ax = A@G (CSR_src), Asq, En; fold global max(En) via atomicMax ----
__device__ __forceinline__ void ax_en_phase(const MP& p, float* gmax) {
  const int t = threadIdx.x;
  const int NT = p.N >> 4;
  const uint4* Gv = (const uint4*)p.Gb;
  for (int tile = blockIdx.x; tile < NT; tile += gridDim.x) {
    const int lane = t & 15;
    const int i = tile * 16 + (t >> 4);
    float axf[8];
    #pragma unroll
    for (int k = 0; k < 8; ++k) axf[k] = 0.f;
    float asq = 0.f;
    int o = p.off_s[i];
    const int oe = p.off_s[i + 1];
    for (; o + 8 <= oe; o += 8) {
      int s[8]; float qv[8]; uint4 r[8];
      #pragma unroll
      for (int j = 0; j < 8; ++j) s[j] = p.idx_s[o + j];
      #pragma unroll
      for (int j = 0; j < 8; ++j) { r[j] = Gv[s[j] * 16 + lane]; qv[j] = p.sq[s[j]]; }
      #pragma unroll
      for (int j = 0; j < 8; ++j) {
        float t8[8]; dec8(r[j], t8);
        asq += qv[j];
        #pragma unroll
        for (int k = 0; k < 8; ++k) axf[k] += t8[k];
      }
    }
    for (; o < oe; ++o) {
      int s = p.idx_s[o];
      float t8[8]; dec8(Gv[s * 16 + lane], t8);
      asq += p.sq[s];
      #pragma unroll
      for (int k = 0; k < 8; ++k) axf[k] += t8[k];
    }
    ((float4*)p.Ax)[i * 32 + lane * 2]     = make_float4(axf[0], axf[1], axf[2], axf[3]);
    ((float4*)p.Ax)[i * 32 + lane * 2 + 1] = make_float4(axf[4], axf[5], axf[6], axf[7]);
    const float4 g0 = ((const float4*)p.G)[i * 32 + lane * 2];
    const float4 g1 = ((const float4*)p.G)[i * 32 + lane * 2 + 1];
    float dot = g0.x * axf[0] + g0.y * axf[1] + g0.z * axf[2] + g0.w * axf[3]
              + g1.x * axf[4] + g1.y * axf[5] + g1.z * axf[6] + g1.w * axf[7];
    dot = grp_sum16(dot);
    if (lane == 0) {
      float en = 0.5f * (p.dego[i] * p.sq[i] + asq - 2.f * dot);
      p.En[i] = en;
      atomicMax((int*)gmax, __float_as_int(en));   // En >= 0: int-max == float-max
    }
  }
}

// ------- softmax stats + combine + relu + LN + GEMM tile -------------------
// W is read directly from L2 (per-block reuse is only 2x; dropping the 32KB
// LDS stage doubles occupancy).
template <int DOUT>
__device__ __forceinline__ void combine_gemm_phase(const MP& p, const float* W,
                                                   const float* gmaxp,
                                                   float* xs, float* s4) {
  const int t = threadIdx.x;
  const int n = p.N;
  const float m = gmaxp[0];
  const float invden = -1.0f / ((m + 1e-12f) * TEMP_);
  float se = 0.f, sl = 0.f;
  for (int k = t; k < n; k += 256) {
    float li = p.En[k] * invden;
    float e = __expf(li);
    se += e; sl += e * li;
  }
  se = blkred(se, s4);
  sl = blkred(sl, s4);
  const float logZ = __logf(se);
  const float S = logZ - sl / se;
  const float cmul = (1.0f / se) * (1.0f / TEMP_);
  const float cadd = S - logZ;

  const uint4* Gv = (const uint4*)p.Gb;
  const int NT = n >> 4;
  for (int tile = blockIdx.x; tile < NT; tile += gridDim.x) {
    __syncthreads();                 // protect xs reuse across tile iterations
    const int lane = t & 15;
    const int i = tile * 16 + (t >> 4);
    const float4 g0 = ((const float4*)p.G)[i * 32 + lane * 2];
    const float4 g1 = ((const float4*)p.G)[i * 32 + lane * 2 + 1];
    const float gi[8] = { g0.x, g0.y, g0.z, g0.w, g1.x, g1.y, g1.z, g1.w };
    float tf[8];
    #pragma unroll
    for (int k = 0; k < 8; ++k) tf[k] = 0.f;
    float atc = 0.f;
    int o = p.off_d[i];
    const int oe = p.off_d[i + 1];
    for (; o + 8 <= oe; o += 8) {
      int s[8]; float ev[8]; uint4 r[8];
      #pragma unroll
      for (int j = 0; j < 8; ++j) s[j] = p.idx_d[o + j];
      #pragma unroll
      for (int j = 0; j < 8; ++j) { r[j] = Gv[s[j] * 16 + lane]; ev[j] = p.En[s[j]]; }
      #pragma unroll
      for (int j = 0; j < 8; ++j) {
        float ls = ev[j] * invden;
        float cs = __expf(ls) * cmul * (ls + cadd);
        atc += cs;
        float t8[8]; dec8(r[j], t8);
        #pragma unroll
        for (int k = 0; k < 8; ++k) tf[k] = fmaf(cs, t8[k], tf[k]);
      }
    }
    for (; o < oe; ++o) {
      int s = p.idx_d[o];
      float ls = p.En[s] * invden;
      float cs = __expf(ls) * cmul * (ls + cadd);
      atc += cs;
      float t8[8]; dec8(Gv[s * 16 + lane], t8);
      #pragma unroll
      for (int k = 0; k < 8; ++k) tf[k] = fmaf(cs, t8[k], tf[k]);
    }
    const float li_i = p.En[i] * invden;
    const float ci = __expf(li_i) * cmul * (li_i + cadd);
    const float dg = p.dego[i];
    const float4 a0 = ((const float4*)p.Ax)[i * 32 + lane * 2];
    const float4 a1 = ((const float4*)p.Ax)[i * 32 + lane * 2 + 1];
    const float axi[8] = { a0.x, a0.y, a0.z, a0.w, a1.x, a1.y, a1.z, a1.w };
    float v[8];
    float ssum = 0.f;
    #pragma unroll
    for (int k = 0; k < 8; ++k) {
      v[k] = fmaxf(gi[k] + ci * (dg * gi[k] - axi[k]) + atc * gi[k] - tf[k], 0.f);
      ssum += v[k];
    }
    float mu = grp_sum16(ssum) * (1.f / 128.f);
    float vsum = 0.f;
    #pragma unroll
    for (int k = 0; k < 8; ++k) {
      v[k] -= mu;
      vsum += v[k] * v[k];
    }
    float var = grp_sum16(vsum) * (1.f / 128.f);
    float rs = rsqrtf(var + LN_EPS_);
    const float4 ga0 = ((const float4*)p.gam)[lane * 2];
    const float4 ga1 = ((const float4*)p.gam)[lane * 2 + 1];
    const float4 be0 = ((const float4*)p.bet)[lane * 2];
    const float4 be1 = ((const float4*)p.bet)[lane * 2 + 1];
    float4 o0, o1;
    o0.x = fmaf(v[0] * rs, ga0.x, be0.x); o0.y = fmaf(v[1] * rs, ga0.y, be0.y);
    o0.z = fmaf(v[2] * rs, ga0.z, be0.z); o0.w = fmaf(v[3] * rs, ga0.w, be0.w);
    o1.x = fmaf(v[4] * rs, ga1.x, be1.x); o1.y = fmaf(v[5] * rs, ga1.y, be1.y);
    o1.z = fmaf(v[6] * rs, ga1.z, be1.z); o1.w = fmaf(v[7] * rs, ga1.w, be1.w);

    // ---- stage LN rows to LDS, then GEMM this 16-row tile ----
    float* xrow = xs + (t >> 4) * 128 + lane * 8;
    ((float4*)xrow)[0] = o0;
    ((float4*)xrow)[1] = o1;
    __syncthreads();

    const int row0 = tile * 16;
    constexpr int RPT = (16 * DOUT) / 256;
    const int c = t % DOUT;
    const int rg = t / DOUT;
    float acc[RPT];
    #pragma unroll
    for (int r = 0; r < RPT; ++r) acc[r] = 0.f;
    #pragma unroll
    for (int kt = 0; kt < 2; ++kt) {
      const float* Wp = W + kt * 64 * DOUT + c;
      #pragma unroll 8
      for (int k = 0; k < 64; ++k) {
        float wv = Wp[k * DOUT];
        #pragma unroll
        for (int r = 0; r < RPT; ++r)
          acc[r] += xs[(rg * RPT + r) * 128 + kt * 64 + k] * wv;
      }
    }
    #pragma unroll
    for (int r = 0; r < RPT; ++r) {
      const int row = row0 + rg * RPT + r;
      p.Hb[row * DOUT + c] = f2bf(p.dinv[row] * acc[r]);   // prescaled output
    }
  }
}

// ------- final conv aggregate (prescaled, DOUT=64): 8 lanes/node -----------
__device__ __forceinline__ void final_agg_phase(const MP& p) {
  const int t = threadIdx.x;
  const int NT32 = p.N >> 5;
  const uint4* Hv = (const uint4*)p.Hb;
  for (int tile = blockIdx.x; tile < NT32; tile += gridDim.x) {
    const int lane = t & 7;
    const int i = tile * 32 + (t >> 3);
    const float di = p.dinv[i];
    float acc[8];
    dec8(Hv[i * 8 + lane], acc);
    int o = p.off_d[i];
    const int oe = p.off_d[i + 1];
    for (; o + 8 <= oe; o += 8) {
      int s[8]; uint4 r[8];
      #pragma unroll
      for (int j = 0; j < 8; ++j) s[j] = p.idx_d[o + j];
      #pragma unroll
      for (int j = 0; j < 8; ++j) r[j] = Hv[s[j] * 8 + lane];
      #pragma unroll
      for (int j = 0; j < 8; ++j) {
        float t8[8]; dec8(r[j], t8);
        #pragma unroll
        for (int k = 0; k < 8; ++k) acc[k] += t8[k];
      }
    }
    for (; o < oe; ++o) {
      int s = p.idx_d[o];
      float t8[8]; dec8(Hv[s * 8 + lane], t8);
      #pragma unroll
      for (int k = 0; k < 8; ++k) acc[k] += t8[k];
    }
    const float4 b0 = ((const float4*)p.bout)[lane * 2];
    const float4 b1 = ((const float4*)p.bout)[lane * 2 + 1];
    float4 r0, r1;
    r0.x = fmaf(di, acc[0], b0.x); r0.y = fmaf(di, acc[1], b0.y);
    r0.z = fmaf(di, acc[2], b0.z); r0.w = fmaf(di, acc[3], b0.w);
    r1.x = fmaf(di, acc[4], b1.x); r1.y = fmaf(di, acc[5], b1.y);
    r1.z = fmaf(di, acc[6], b1.z); r1.w = fmaf(di, acc[7], b1.w);
    ((float4*)p.out)[i * 16 + lane * 2]     = r0;
    ((float4*)p.out)[i * 16 + lane * 2 + 1] = r1;
  }
}

// =================== kernel 1: hist + scan + gemm1 + fill ==================
__global__ __launch_bounds__(256, 4) void k_setup(MP p) {
  __shared__ float xs[16 * DH];
  __shared__ int ws4[4];
  const int t = threadIdx.x;
  const int nb = gridDim.x;
  const int N = p.N, E = p.E;

  // ---- P1: degree histogram (cnt_* zeroed by host memset) ----
  for (int e = blockIdx.x * 256 + t; e < E; e += nb * 256) {
    atomicAdd(&p.cnt_s[p.ei[e]], 1);
    atomicAdd(&p.cnt_d[p.ei[E + e]], 1);
  }
  gsync(p.bar, 1u);

  // ---- P2: hierarchical scan A (blocks 0..63: 32 per direction) ----
  if (blockIdx.x < 64) {
    const int dir = blockIdx.x >> 5, blk = blockIdx.x & 31;
    const int* cnt = dir ? p.cnt_s : p.cnt_d;
    int* off = dir ? p.off_s : p.off_d;
    const int NPB = (N + 31) >> 5;
    const int i = blk * NPB + t;
    const bool valid = (t < NPB) && (i < N);
    int tot = valid ? cnt[i] : 0;
    const int lane = t & 63, w = t >> 6;
    int v = tot;
    #pragma unroll
    for (int o = 1; o < 64; o <<= 1) {
      int u = __shfl_up(v, o, 64);
      if (lane >= o) v += u;
    }
    if (lane == 63) ws4[w] = v;
    __syncthreads();
    int wbase = 0;
    #pragma unroll
    for (int k = 0; k < 4; ++k) wbase += (k < w) ? ws4[k] : 0;
    const int excl = wbase + v - tot;
    if (valid) {
      off[i] = excl;                          // temp: block-local prefix
      if (dir == 0) p.dinv[i] = rsqrtf((float)tot + 1.0f);
      else          p.dego[i] = (float)tot;
    }
    if (t == 0) {
      int bt = 0;
      #pragma unroll
      for (int k = 0; k < 4; ++k) bt += ws4[k];
      p.bsum[dir * 32 + blk] = bt;
    }
  }
  gsync(p.bar, 2u);

  // ---- P3: scan B — finalize offsets, zero cnt (fill cursors) ----
  if (blockIdx.x < 64) {
    const int dir = blockIdx.x >> 5, blk = blockIdx.x & 31;
    int* cnt = dir ? p.cnt_s : p.cnt_d;
    int* off = dir ? p.off_s : p.off_d;
    if (t == 0) {
      int s = 0;
      for (int k = 0; k < blk; ++k) s += p.bsum[dir * 32 + k];
      ws4[0] = s;
    }
    __syncthreads();
    const int bbase = ws4[0];
    const int NPB = (N + 31) >> 5;
    const int i = blk * NPB + t;
    if (t < NPB && i < N) {
      off[i] = bbase + off[i];
      cnt[i] = 0;
    }
    if (t == 1 && blk == 31) {
      int s = 0;
      for (int k = 0; k < 32; ++k) s += p.bsum[dir * 32 + k];
      off[N] = s;
    }
  }
  gsync(p.bar, 3u);

  // ---- P4: layer-1 GEMM with dinv prescale (W1 direct from L2) ----
  const int NT = N >> 4;
  for (int tile = blockIdx.x; tile < NT; tile += nb) {
    __syncthreads();
    const int row0 = tile * 16;
    const float4* xg = (const float4*)(p.x + row0 * DH);
    float4* xs4 = (float4*)xs;
    xs4[t] = xg[t];
    xs4[t + 256] = xg[t + 256];
    __syncthreads();
    const int c = t & 127, rg = t >> 7;   // RPT = 8
    float acc[8];
    #pragma unroll
    for (int r = 0; r < 8; ++r) acc[r] = 0.f;
    #pragma unroll
    for (int kt = 0; kt < 2; ++kt) {
      const float* Wp = p.W1 + kt * 64 * DH + c;
      #pragma unroll 8
      for (int k = 0; k < 64; ++k) {
        float wv = Wp[k * DH];
        #pragma unroll
        for (int r = 0; r < 8; ++r)
          acc[r] += xs[(rg * 8 + r) * DH + kt * 64 + k] * wv;
      }
    }
    #pragma unroll
    for (int r = 0; r < 8; ++r) {
      const int row = row0 + rg * 8 + r;
      p.Hb[row * DH + c] = f2bf(p.dinv[row] * acc[r]);
    }
  }
  // ---- CSR fill ----
  for (int e = blockIdx.x * 256 + t; e < E; e += nb * 256) {
    int s = p.ei[e], d = p.ei[E + e];
    int pp = atomicAdd(&p.cnt_d[d], 1);
    p.idx_d[p.off_d[d] + pp] = s;
    int q = atomicAdd(&p.cnt_s[s], 1);
    p.idx_s[p.off_s[s] + q] = d;
  }
}

// =================== kernel 2/3: one GCN+entropy layer =====================
// BBASE: number of barriers already consumed by earlier kernels (monotonic).
template <int DOUT, bool FINAL, unsigned int BBASE>
__global__ __launch_bounds__(256, 4) void k_layer(MP p, const float* bias,
                                                  const float* W, float* gmaxp) {
  __shared__ float xs[16 * DH];
  __shared__ float s4[4];
  conv_agg_phase(p, bias);
  gsync(p.bar, BBASE + 1u);
  ax_en_phase(p, gmaxp);
  gsync(p.bar, BBASE + 2u);
  combine_gemm_phase<DOUT>(p, W, gmaxp, xs, s4);
  if (FINAL) {
    gsync(p.bar, BBASE + 3u);
    final_agg_phase(p);
  }
}

extern "C" void kernel_launch(void* const* d_in, const int* in_sizes, int n_in,
                              void* d_out, int out_size, void* d_ws, size_t ws_size,
                              hipStream_t stream) {
  MP p;
  p.x    = (const float*)d_in[0];
  p.ei   = (const int*)d_in[1];
  p.W1   = (const float*)d_in[2];
  p.b1   = (const float*)d_in[3];
  p.W2   = (const float*)d_in[4];
  p.b2   = (const float*)d_in[5];
  p.Wout = (const float*)d_in[6];
  p.bout = (const float*)d_in[7];
  p.gam  = (const float*)d_in[8];
  p.bet  = (const float*)d_in[9];
  p.out  = (float*)d_out;

  const int N = in_sizes[0] / DH;   // 8000
  const int E = in_sizes[1] / 2;    // 256000
  p.N = N; p.E = E;

  float* ws = (float*)d_ws;
  p.G  = ws;   ws += N * DH;
  p.Ax = ws;   ws += N * DH;
  p.sq = ws;   ws += N;
  p.En = ws;   ws += N;
  p.dinv = ws; ws += N;
  p.dego = ws; ws += N;
  p.Hb = (unsigned short*)ws; ws += N * DH / 2;   // bf16 N x 128
  p.Gb = (unsigned short*)ws; ws += N * DH / 2;   // bf16 N x 128
  p.cnt_d = (int*)ws; ws += N;
  p.cnt_s = (int*)ws; ws += N;
  p.gmax  = (float*)ws; ws += 2;                  // [0]=layer0 max, [1]=layer1 max
  p.bar   = (unsigned int*)ws; ws += 4224;        // cells + root + gen + cgen
  p.off_d = (int*)ws; ws += N + 4;
  p.off_s = (int*)ws; ws += N + 4;
  p.bsum  = (int*)ws; ws += 64;
  p.idx_d = (int*)ws; ws += E;
  p.idx_s = (int*)ws; ws += E;

  // Same grid for all kernels (barrier quota consistency: counters are
  // monotonic across kernels, so quota = nb/64 must not change).
  int mb1 = 0, mb2 = 0, mb3 = 0;
  (void)hipOccupancyMaxActiveBlocksPerMultiprocessor(&mb1, k_setup, 256, 0);
  (void)hipOccupancyMaxActiveBlocksPerMultiprocessor(&mb2, k_layer<DH, false, 3u>, 256, 0);
  (void)hipOccupancyMaxActiveBlocksPerMultiprocessor(&mb3, k_layer<64, true, 5u>, 256, 0);
  int mb = mb1;
  if (mb2 < mb) mb = mb2;
  if (mb3 < mb) mb = mb3;
  if (mb <= 0) mb = 2;
  int nb = mb * 256;                // multiple of 64 by construction
  if (nb > 2048) nb = 2048;

  // zero cnt_d, cnt_s, gmax[2], bar[4224] (contiguous)
  hipMemsetAsync(p.cnt_d, 0, (size_t)(2 * N + 2 + 4224) * sizeof(int), stream);
  k_setup<<<nb, 256, 0, stream>>>(p);
  k_layer<DH, false, 3u><<<nb, 256, 0, stream>>>(p, p.b1, p.W2, p.gmax);
  k_layer<64, true, 5u><<<nb, 256, 0, stream>>>(p, p.b2, p.Wout, p.gmax + 1);
}

// Round 4
// 271.982 us; speedup vs baseline: 2.1698x; 1.3001x over previous
//
#include <hip/hip_runtime.h>
#include <hip/hip_bf16.h>

#define DH 128

static constexpr float TEMP_ = 10.0f;
static constexpr float LN_EPS_ = 1e-5f;

// ---------------- bf16 helpers ----------------
__device__ __forceinline__ unsigned short f2bf(float f) {
  union { float f; unsigned int i; } v; v.f = f;
  unsigned int b = v.i + 0x7FFFu + ((v.i >> 16) & 1u);   // RNE
  return (unsigned short)(b >> 16);
}
__device__ __forceinline__ void dec2(unsigned int u, float& lo, float& hi) {
  union { unsigned int i; float f; } a, b;
  a.i = u << 16; b.i = u & 0xFFFF0000u;
  lo = a.f; hi = b.f;
}
__device__ __forceinline__ void dec8(uint4 u, float* o) {
  dec2(u.x, o[0], o[1]); dec2(u.y, o[2], o[3]);
  dec2(u.z, o[4], o[5]); dec2(u.w, o[6], o[7]);
}
__device__ __forceinline__ unsigned int pack2(float lo, float hi) {
  return (unsigned int)f2bf(lo) | ((unsigned int)f2bf(hi) << 16);
}

__device__ __forceinline__ float grp_sum16(float v) {
  #pragma unroll
  for (int o = 8; o > 0; o >>= 1) v += __shfl_down(v, o, 16);
  return __shfl(v, 0, 16);
}

// 256-thread block sum-reduce; s4 = 4-float LDS scratch. Returns to all.
__device__ __forceinline__ float blkred(float v, float* s4) {
  const int t = threadIdx.x;
  #pragma unroll
  for (int o = 32; o > 0; o >>= 1) v += __shfl_down(v, o, 64);
  __syncthreads();
  if ((t & 63) == 0) s4[t >> 6] = v;
  __syncthreads();
  float r = (s4[0] + s4[1]) + (s4[2] + s4[3]);
  __syncthreads();
  return r;
}

// ---------------- degree histogram ----------------
__global__ void k_hist(const int* __restrict__ ei, int E, int* cnt_d, int* cnt_s) {
  for (int e = blockIdx.x * 256 + threadIdx.x; e < E; e += gridDim.x * 256) {
    atomicAdd(&cnt_s[ei[e]], 1);
    atomicAdd(&cnt_d[ei[E + e]], 1);
  }
}

// ---------- hierarchical scan A: 64 blocks (32/dir), ~250 nodes each ----------
__global__ __launch_bounds__(256) void k_scan_a(const int* __restrict__ cnt_d,
                                                const int* __restrict__ cnt_s,
                                                int* off_d, int* off_s, int* bsum,
                                                float* dinv, float* dego, int n) {
  __shared__ int ws4[4];
  const int t = threadIdx.x;
  const int dir = blockIdx.x >> 5, blk = blockIdx.x & 31;
  const int* cnt = dir ? cnt_s : cnt_d;
  int* off = dir ? off_s : off_d;
  const int NPB = (n + 31) >> 5;           // 250 for n=8000
  const int i = blk * NPB + t;
  const bool valid = (t < NPB) && (i < n);
  int tot = valid ? cnt[i] : 0;
  const int lane = t & 63, w = t >> 6;
  int v = tot;
  #pragma unroll
  for (int o = 1; o < 64; o <<= 1) {
    int u = __shfl_up(v, o, 64);
    if (lane >= o) v += u;
  }
  if (lane == 63) ws4[w] = v;
  __syncthreads();
  int wbase = 0;
  #pragma unroll
  for (int k = 0; k < 4; ++k) wbase += (k < w) ? ws4[k] : 0;
  const int excl = wbase + v - tot;
  if (valid) {
    off[i] = excl;                          // temp: block-local prefix
    if (dir == 0) dinv[i] = rsqrtf((float)tot + 1.0f);
    else          dego[i] = (float)tot;
  }
  if (t == 0) {
    int bt = 0;
    #pragma unroll
    for (int k = 0; k < 4; ++k) bt += ws4[k];
    bsum[dir * 32 + blk] = bt;
  }
}

// ---------- hierarchical scan B: finalize offsets, zero cnt (fill cursors) ----
__global__ __launch_bounds__(256) void k_scan_b(int* cnt_d, int* cnt_s,
                                                int* off_d, int* off_s,
                                                const int* __restrict__ bsum, int n) {
  __shared__ int sb;
  const int t = threadIdx.x;
  const int dir = blockIdx.x >> 5, blk = blockIdx.x & 31;
  int* cnt = dir ? cnt_s : cnt_d;
  int* off = dir ? off_s : off_d;
  if (t == 0) {
    int s = 0;
    for (int k = 0; k < blk; ++k) s += bsum[dir * 32 + k];
    sb = s;
  }
  __syncthreads();
  const int bbase = sb;
  const int NPB = (n + 31) >> 5;
  const int i = blk * NPB + t;
  if (t < NPB && i < n) {
    off[i] = bbase + off[i];
    cnt[i] = 0;
  }
  if (t == 1 && blk == 31) {
    int s = 0;
    for (int k = 0; k < 32; ++k) s += bsum[dir * 32 + k];
    off[n] = s;
  }
}

// ---- fused: layer-1 GEMM with dinv prescale (blocks < NT) + CSR fill ------
// Hbs[i] = dinv[i] * (X @ W1)[i]  (bf16)
__global__ __launch_bounds__(256) void k_gemm1_fill(const float* __restrict__ X,
                                                    const float* __restrict__ W,
                                                    const float* __restrict__ dinv,
                                                    unsigned short* __restrict__ Hb,
                                                    const int* __restrict__ ei, int E,
                                                    const int* __restrict__ off_d,
                                                    const int* __restrict__ off_s,
                                                    int* cnt_d, int* cnt_s,
                                                    int* idx_d, int* idx_s, int NT) {
  __shared__ float Ws[64 * DH];
  __shared__ float xs[16 * 128];
  const int t = threadIdx.x;
  if ((int)blockIdx.x < NT) {
    const int row0 = blockIdx.x * 16;
    const float4* xg = (const float4*)(X + row0 * 128);
    float4* xs4 = (float4*)xs;
    xs4[t] = xg[t];
    xs4[t + 256] = xg[t + 256];
    const int c = t & 127, rg = t >> 7;   // RPT = 8
    float acc[8];
    #pragma unroll
    for (int r = 0; r < 8; ++r) acc[r] = 0.f;
    for (int kt = 0; kt < 2; ++kt) {
      __syncthreads();
      for (int i = t; i < 64 * DH; i += 256) Ws[i] = W[kt * 64 * DH + i];
      __syncthreads();
      for (int k = 0; k < 64; ++k) {
        float wv = Ws[k * DH + c];
        #pragma unroll
        for (int r = 0; r < 8; ++r)
          acc[r] += xs[(rg * 8 + r) * 128 + kt * 64 + k] * wv;
      }
    }
    #pragma unroll
    for (int r = 0; r < 8; ++r) {
      const int row = row0 + rg * 8 + r;
      Hb[row * DH + c] = f2bf(dinv[row] * acc[r]);
    }
  } else {
    const int nb = gridDim.x - NT;
    for (int e = (blockIdx.x - NT) * 256 + t; e < E; e += nb * 256) {
      int s = ei[e], d = ei[E + e];
      int p = atomicAdd(&cnt_d[d], 1);
      idx_d[off_d[d] + p] = s;
      int q = atomicAdd(&cnt_s[s], 1);
      idx_s[off_s[s] + q] = d;
    }
  }
}

// ------- conv aggregate (prescaled rows): 16 lanes/node, uint4/lane --------
// G_i = b + dinv_i * (Hbs[i] + sum_{s in in(i)} Hbs[s])
__global__ __launch_bounds__(256) void k_conv_agg(const unsigned short* __restrict__ Hb,
                                                  const float* __restrict__ dinv,
                                                  const float* __restrict__ b,
                                                  const int* __restrict__ off_d,
                                                  const int* __restrict__ idx_d,
                                                  float* __restrict__ G,
                                                  unsigned short* __restrict__ Gb,
                                                  float* __restrict__ sq) {
  const int lane = threadIdx.x & 15;
  const int i = blockIdx.x * 16 + (threadIdx.x >> 4);
  const uint4* Hv = (const uint4*)Hb;
  const float di = dinv[i];
  float acc[8];
  dec8(Hv[i * 16 + lane], acc);              // self row (already dinv-scaled)
  int o = off_d[i];
  const int oe = off_d[i + 1];
  for (; o + 8 <= oe; o += 8) {
    int s[8]; uint4 r[8];
    #pragma unroll
    for (int j = 0; j < 8; ++j) s[j] = idx_d[o + j];
    #pragma unroll
    for (int j = 0; j < 8; ++j) r[j] = Hv[s[j] * 16 + lane];
    #pragma unroll
    for (int j = 0; j < 8; ++j) {
      float t8[8]; dec8(r[j], t8);
      #pragma unroll
      for (int k = 0; k < 8; ++k) acc[k] += t8[k];
    }
  }
  for (; o < oe; ++o) {
    int s = idx_d[o];
    float t8[8]; dec8(Hv[s * 16 + lane], t8);
    #pragma unroll
    for (int k = 0; k < 8; ++k) acc[k] += t8[k];
  }
  const float4 b0 = ((const float4*)b)[lane * 2];
  const float4 b1 = ((const float4*)b)[lane * 2 + 1];
  float gi[8];
  gi[0] = fmaf(di, acc[0], b0.x); gi[1] = fmaf(di, acc[1], b0.y);
  gi[2] = fmaf(di, acc[2], b0.z); gi[3] = fmaf(di, acc[3], b0.w);
  gi[4] = fmaf(di, acc[4], b1.x); gi[5] = fmaf(di, acc[5], b1.y);
  gi[6] = fmaf(di, acc[6], b1.z); gi[7] = fmaf(di, acc[7], b1.w);
  ((float4*)G)[i * 32 + lane * 2]     = make_float4(gi[0], gi[1], gi[2], gi[3]);
  ((float4*)G)[i * 32 + lane * 2 + 1] = make_float4(gi[4], gi[5], gi[6], gi[7]);
  uint4 gp;
  gp.x = pack2(gi[0], gi[1]); gp.y = pack2(gi[2], gi[3]);
  gp.z = pack2(gi[4], gi[5]); gp.w = pack2(gi[6], gi[7]);
  ((uint4*)Gb)[i * 16 + lane] = gp;
  float s2 = 0.f;
  #pragma unroll
  for (int k = 0; k < 8; ++k) s2 += gi[k] * gi[k];
  s2 = grp_sum16(s2);
  if (lane == 0) sq[i] = s2;
}

// ------- Ax = A@G (CSR_src), Asq, En; fold global max(En) via atomicMax ----
__global__ __launch_bounds__(256) void k_ax_en(const float* __restrict__ G,
                                               const unsigned short* __restrict__ Gb,
                                               const float* __restrict__ sq,
                                               const float* __restrict__ dego,
                                               const int* __restrict__ off_s,
                                               const int* __restrict__ idx_s,
                                               float* __restrict__ Ax,
                                               float* __restrict__ En,
                                               float* __restrict__ gmax) {
  const int lane = threadIdx.x & 15;
  const int i = blockIdx.x * 16 + (threadIdx.x >> 4);
  const uint4* Gv = (const uint4*)Gb;
  float axf[8];
  #pragma unroll
  for (int k = 0; k < 8; ++k) axf[k] = 0.f;
  float asq = 0.f;
  int o = off_s[i];
  const int oe = off_s[i + 1];
  for (; o + 8 <= oe; o += 8) {
    int s[8]; float qv[8]; uint4 r[8];
    #pragma unroll
    for (int j = 0; j < 8; ++j) s[j] = idx_s[o + j];
    #pragma unroll
    for (int j = 0; j < 8; ++j) { r[j] = Gv[s[j] * 16 + lane]; qv[j] = sq[s[j]]; }
    #pragma unroll
    for (int j = 0; j < 8; ++j) {
      float t8[8]; dec8(r[j], t8);
      asq += qv[j];
      #pragma unroll
      for (int k = 0; k < 8; ++k) axf[k] += t8[k];
    }
  }
  for (; o < oe; ++o) {
    int s = idx_s[o];
    float t8[8]; dec8(Gv[s * 16 + lane], t8);
    asq += sq[s];
    #pragma unroll
    for (int k = 0; k < 8; ++k) axf[k] += t8[k];
  }
  ((float4*)Ax)[i * 32 + lane * 2]     = make_float4(axf[0], axf[1], axf[2], axf[3]);
  ((float4*)Ax)[i * 32 + lane * 2 + 1] = make_float4(axf[4], axf[5], axf[6], axf[7]);
  const float4 g0 = ((const float4*)G)[i * 32 + lane * 2];
  const float4 g1 = ((const float4*)G)[i * 32 + lane * 2 + 1];
  float dot = g0.x * axf[0] + g0.y * axf[1] + g0.z * axf[2] + g0.w * axf[3]
            + g1.x * axf[4] + g1.y * axf[5] + g1.z * axf[6] + g1.w * axf[7];
  dot = grp_sum16(dot);
  if (lane == 0) {
    float en = 0.5f * (dego[i] * sq[i] + asq - 2.f * dot);
    En[i] = en;
    atomicMax((int*)gmax, __float_as_int(en));   // En >= 0: int-max == float-max
  }
}

// ------- fused: softmax stats + combine + relu + LN + GEMM tile ------------
// Block = 16 nodes (16 lanes x 8 feats each) = one 16-row GEMM tile.
// Global max(En) precomputed by k_ax_en (gmaxp); W read directly from L2
// (per-block reuse is only 2x -> no 32KB LDS stage, higher occupancy).
template <int DOUT>
__global__ __launch_bounds__(256) void k_combine_gemm(const float* __restrict__ G,
                                                      const unsigned short* __restrict__ Gb,
                                                      const float* __restrict__ Ax,
                                                      const float* __restrict__ En,
                                                      const float* __restrict__ dego,
                                                      const float* __restrict__ dinv,
                                                      const int* __restrict__ off_d,
                                                      const int* __restrict__ idx_d,
                                                      const float* __restrict__ gamma,
                                                      const float* __restrict__ beta,
                                                      const float* __restrict__ W,
                                                      unsigned short* __restrict__ Hb,
                                                      const float* __restrict__ gmaxp,
                                                      int n) {
  __shared__ float xs[16 * 128];
  __shared__ float s4[4];
  const int t = threadIdx.x;
  // ---- softmax statistics prologue (max already global via k_ax_en) ----
  const float m = gmaxp[0];
  const float invden = -1.0f / ((m + 1e-12f) * TEMP_);   // li = En*invden
  float se = 0.f, sl = 0.f;
  for (int k = t; k < n; k += 256) {
    float li = En[k] * invden;
    float e = __expf(li);
    se += e; sl += e * li;
  }
  se = blkred(se, s4);
  sl = blkred(sl, s4);
  const float logZ = __logf(se);
  const float S = logZ - sl / se;
  const float cmul = (1.0f / se) * (1.0f / TEMP_);
  const float cadd = S - logZ;

  // ---- per-node combine + LN ----
  const int lane = t & 15;
  const int i = blockIdx.x * 16 + (t >> 4);
  const uint4* Gv = (const uint4*)Gb;
  const float4 g0 = ((const float4*)G)[i * 32 + lane * 2];
  const float4 g1 = ((const float4*)G)[i * 32 + lane * 2 + 1];
  const float gi[8] = { g0.x, g0.y, g0.z, g0.w, g1.x, g1.y, g1.z, g1.w };
  float tf[8];
  #pragma unroll
  for (int k = 0; k < 8; ++k) tf[k] = 0.f;
  float atc = 0.f;
  int o = off_d[i];
  const int oe = off_d[i + 1];
  for (; o + 8 <= oe; o += 8) {
    int s[8]; float ev[8]; uint4 r[8];
    #pragma unroll
    for (int j = 0; j < 8; ++j) s[j] = idx_d[o + j];
    #pragma unroll
    for (int j = 0; j < 8; ++j) { r[j] = Gv[s[j] * 16 + lane]; ev[j] = En[s[j]]; }
    #pragma unroll
    for (int j = 0; j < 8; ++j) {
      float ls = ev[j] * invden;
      float cs = __expf(ls) * cmul * (ls + cadd);
      atc += cs;
      float t8[8]; dec8(r[j], t8);
      #pragma unroll
      for (int k = 0; k < 8; ++k) tf[k] = fmaf(cs, t8[k], tf[k]);
    }
  }
  for (; o < oe; ++o) {
    int s = idx_d[o];
    float ls = En[s] * invden;
    float cs = __expf(ls) * cmul * (ls + cadd);
    atc += cs;
    float t8[8]; dec8(Gv[s * 16 + lane], t8);
    #pragma unroll
    for (int k = 0; k < 8; ++k) tf[k] = fmaf(cs, t8[k], tf[k]);
  }
  const float li_i = En[i] * invden;
  const float ci = __expf(li_i) * cmul * (li_i + cadd);
  const float dg = dego[i];
  const float4 a0 = ((const float4*)Ax)[i * 32 + lane * 2];
  const float4 a1 = ((const float4*)Ax)[i * 32 + lane * 2 + 1];
  const float axi[8] = { a0.x, a0.y, a0.z, a0.w, a1.x, a1.y, a1.z, a1.w };
  float v[8];
  float ssum = 0.f;
  #pragma unroll
  for (int k = 0; k < 8; ++k) {
    v[k] = fmaxf(gi[k] + ci * (dg * gi[k] - axi[k]) + atc * gi[k] - tf[k], 0.f);
    ssum += v[k];
  }
  float mu = grp_sum16(ssum) * (1.f / 128.f);
  float vsum = 0.f;
  #pragma unroll
  for (int k = 0; k < 8; ++k) {
    v[k] -= mu;
    vsum += v[k] * v[k];
  }
  float var = grp_sum16(vsum) * (1.f / 128.f);
  float rs = rsqrtf(var + LN_EPS_);
  const float4 ga0 = ((const float4*)gamma)[lane * 2];
  const float4 ga1 = ((const float4*)gamma)[lane * 2 + 1];
  const float4 be0 = ((const float4*)beta)[lane * 2];
  const float4 be1 = ((const float4*)beta)[lane * 2 + 1];
  float4 o0, o1;
  o0.x = fmaf(v[0] * rs, ga0.x, be0.x); o0.y = fmaf(v[1] * rs, ga0.y, be0.y);
  o0.z = fmaf(v[2] * rs, ga0.z, be0.z); o0.w = fmaf(v[3] * rs, ga0.w, be0.w);
  o1.x = fmaf(v[4] * rs, ga1.x, be1.x); o1.y = fmaf(v[5] * rs, ga1.y, be1.y);
  o1.z = fmaf(v[6] * rs, ga1.z, be1.z); o1.w = fmaf(v[7] * rs, ga1.w, be1.w);

  // ---- stage LN rows to LDS, then GEMM this 16-row tile ----
  float* xrow = xs + (t >> 4) * 128 + lane * 8;
  ((float4*)xrow)[0] = o0;
  ((float4*)xrow)[1] = o1;
  __syncthreads();

  const int row0 = blockIdx.x * 16;
  constexpr int RPT = (16 * DOUT) / 256;
  const int c = t % DOUT;
  const int rg = t / DOUT;
  float acc[RPT];
  #pragma unroll
  for (int r = 0; r < RPT; ++r) acc[r] = 0.f;
  #pragma unroll
  for (int kt = 0; kt < 2; ++kt) {
    const float* Wp = W + kt * 64 * DOUT + c;
    #pragma unroll 8
    for (int k = 0; k < 64; ++k) {
      float wv = Wp[k * DOUT];
      #pragma unroll
      for (int r = 0; r < RPT; ++r)
        acc[r] += xs[(rg * RPT + r) * 128 + kt * 64 + k] * wv;
    }
  }
  #pragma unroll
  for (int r = 0; r < RPT; ++r) {
    const int row = row0 + rg * RPT + r;
    Hb[row * DOUT + c] = f2bf(dinv[row] * acc[r]);   // prescaled output
  }
}

// ------- final conv aggregate (prescaled, DOUT=64): 8 lanes/node -----------
__global__ __launch_bounds__(256) void k_final_agg(const unsigned short* __restrict__ Hb,
                                                   const float* __restrict__ dinv,
                                                   const float* __restrict__ bout,
                                                   const int* __restrict__ off_d,
                                                   const int* __restrict__ idx_d,
                                                   float* __restrict__ out) {
  const int lane = threadIdx.x & 7;
  const int i = blockIdx.x * 32 + (threadIdx.x >> 3);
  const uint4* Hv = (const uint4*)Hb;
  const float di = dinv[i];
  float acc[8];
  dec8(Hv[i * 8 + lane], acc);               // self row (already dinv-scaled)
  int o = off_d[i];
  const int oe = off_d[i + 1];
  for (; o + 8 <= oe; o += 8) {
    int s[8]; uint4 r[8];
    #pragma unroll
    for (int j = 0; j < 8; ++j) s[j] = idx_d[o + j];
    #pragma unroll
    for (int j = 0; j < 8; ++j) r[j] = Hv[s[j] * 8 + lane];
    #pragma unroll
    for (int j = 0; j < 8; ++j) {
      float t8[8]; dec8(r[j], t8);
      #pragma unroll
      for (int k = 0; k < 8; ++k) acc[k] += t8[k];
    }
  }
  for (; o < oe; ++o) {
    int s = idx_d[o];
    float t8[8]; dec8(Hv[s * 8 + lane], t8);
    #pragma unroll
    for (int k = 0; k < 8; ++k) acc[k] += t8[k];
  }
  const float4 b0 = ((const float4*)bout)[lane * 2];
  const float4 b1 = ((const float4*)bout)[lane * 2 + 1];
  float4 r0, r1;
  r0.x = fmaf(di, acc[0], b0.x); r0.y = fmaf(di, acc[1], b0.y);
  r0.z = fmaf(di, acc[2], b0.z); r0.w = fmaf(di, acc[3], b0.w);
  r1.x = fmaf(di, acc[4], b1.x); r1.y = fmaf(di, acc[5], b1.y);
  r1.z = fmaf(di, acc[6], b1.z); r1.w = fmaf(di, acc[7], b1.w);
  ((float4*)out)[i * 16 + lane * 2]     = r0;
  ((float4*)out)[i * 16 + lane * 2 + 1] = r1;
}

extern "C" void kernel_launch(void* const* d_in, const int* in_sizes, int n_in,
                              void* d_out, int out_size, void* d_ws, size_t ws_size,
                              hipStream_t stream) {
  const float* x    = (const float*)d_in[0];
  const int*   ei   = (const int*)d_in[1];
  const float* W1   = (const float*)d_in[2];
  const float* b1   = (const float*)d_in[3];
  const float* W2   = (const float*)d_in[4];
  const float* b2   = (const float*)d_in[5];
  const float* Wout = (const float*)d_in[6];
  const float* bout = (const float*)d_in[7];
  const float* gam  = (const float*)d_in[8];
  const float* bet  = (const float*)d_in[9];
  float* out = (float*)d_out;

  const int N = in_sizes[0] / DH;   // 8000
  const int E = in_sizes[1] / 2;    // 256000

  float* ws = (float*)d_ws;
  float* G  = ws;   ws += N * DH;
  float* Ax = ws;   ws += N * DH;
  float* sq = ws;   ws += N;
  float* En = ws;   ws += N;
  float* dinv = ws; ws += N;
  float* dego = ws; ws += N;
  unsigned short* Hb = (unsigned short*)ws; ws += N * DH / 2;   // bf16 N x 128
  unsigned short* Gb = (unsigned short*)ws; ws += N * DH / 2;   // bf16 N x 128
  int* cnt_d  = (int*)ws; ws += N;
  int* cnt_s  = (int*)ws; ws += N;
  float* gmax = (float*)ws; ws += 2;   // [0]=layer0 max, [1]=layer1 max
  int* off_d  = (int*)ws; ws += N + 4;
  int* off_s  = (int*)ws; ws += N + 4;
  int* bsum   = (int*)ws; ws += 64;
  int* idx_d  = (int*)ws; ws += E;
  int* idx_s  = (int*)ws; ws += E;

  const int NT = N / 16;            // 500 gemm tile blocks

  // zero cnt_d, cnt_s, gmax (contiguous)
  hipMemsetAsync(cnt_d, 0, (size_t)(2 * N + 2) * sizeof(int), stream);
  k_hist<<<256, 256, 0, stream>>>(ei, E, cnt_d, cnt_s);
  k_scan_a<<<64, 256, 0, stream>>>(cnt_d, cnt_s, off_d, off_s, bsum, dinv, dego, N);
  k_scan_b<<<64, 256, 0, stream>>>(cnt_d, cnt_s, off_d, off_s, bsum, N);
  k_gemm1_fill<<<NT + (E + 255) / 256, 256, 0, stream>>>(x, W1, dinv, Hb, ei, E,
                                                         off_d, off_s, cnt_d, cnt_s,
                                                         idx_d, idx_s, NT);

  // layer 0
  k_conv_agg<<<N / 16, 256, 0, stream>>>(Hb, dinv, b1, off_d, idx_d, G, Gb, sq);
  k_ax_en<<<N / 16, 256, 0, stream>>>(G, Gb, sq, dego, off_s, idx_s, Ax, En, gmax);
  k_combine_gemm<128><<<N / 16, 256, 0, stream>>>(G, Gb, Ax, En, dego, dinv, off_d,
                                                  idx_d, gam, bet, W2, Hb, gmax, N);
  // layer 1
  k_conv_agg<<<N / 16, 256, 0, stream>>>(Hb, dinv, b2, off_d, idx_d, G, Gb, sq);
  k_ax_en<<<N / 16, 256, 0, stream>>>(G, Gb, sq, dego, off_s, idx_s, Ax, En, gmax + 1);
  k_combine_gemm<64><<<N / 16, 256, 0, stream>>>(G, Gb, Ax, En, dego, dinv, off_d,
                                                 idx_d, gam, bet, Wout, Hb, gmax + 1, N);
  k_final_agg<<<N / 32, 256, 0, stream>>>(Hb, dinv, bout, off_d, idx_d, out);
}

// Round 5
// 244.730 us; speedup vs baseline: 2.4114x; 1.1114x over previous
//
#include <hip/hip_runtime.h>
#include <hip/hip_bf16.h>

#define DH 128

static constexpr float TEMP_ = 10.0f;
static constexpr float LN_EPS_ = 1e-5f;

// ---------------- bf16 helpers ----------------
__device__ __forceinline__ unsigned short f2bf(float f) {
  union { float f; unsigned int i; } v; v.f = f;
  unsigned int b = v.i + 0x7FFFu + ((v.i >> 16) & 1u);   // RNE
  return (unsigned short)(b >> 16);
}
__device__ __forceinline__ void dec2(unsigned int u, float& lo, float& hi) {
  union { unsigned int i; float f; } a, b;
  a.i = u << 16; b.i = u & 0xFFFF0000u;
  lo = a.f; hi = b.f;
}
__device__ __forceinline__ void dec8(uint4 u, float* o) {
  dec2(u.x, o[0], o[1]); dec2(u.y, o[2], o[3]);
  dec2(u.z, o[4], o[5]); dec2(u.w, o[6], o[7]);
}
__device__ __forceinline__ unsigned int pack2(float lo, float hi) {
  return (unsigned int)f2bf(lo) | ((unsigned int)f2bf(hi) << 16);
}

__device__ __forceinline__ float grp_sum16(float v) {
  #pragma unroll
  for (int o = 8; o > 0; o >>= 1) v += __shfl_down(v, o, 16);
  return __shfl(v, 0, 16);
}

// 256-thread block sum-reduce; s4 = 4-float LDS scratch. Returns to all.
__device__ __forceinline__ float blkred(float v, float* s4) {
  const int t = threadIdx.x;
  #pragma unroll
  for (int o = 32; o > 0; o >>= 1) v += __shfl_down(v, o, 64);
  __syncthreads();
  if ((t & 63) == 0) s4[t >> 6] = v;
  __syncthreads();
  float r = (s4[0] + s4[1]) + (s4[2] + s4[3]);
  __syncthreads();
  return r;
}

// ---------------- degree histogram ----------------
__global__ void k_hist(const int* __restrict__ ei, int E, int* cnt_d, int* cnt_s) {
  for (int e = blockIdx.x * 256 + threadIdx.x; e < E; e += gridDim.x * 256) {
    atomicAdd(&cnt_s[ei[e]], 1);
    atomicAdd(&cnt_d[ei[E + e]], 1);
  }
}

// ---------- fused scan: 2 blocks x 1024 threads, one block per direction ----
// Produces off (exclusive prefix + total at off[n]), dinv/dego, zeroes cnt.
__global__ __launch_bounds__(1024) void k_scan(int* cnt_d, int* cnt_s,
                                               int* off_d, int* off_s,
                                               float* dinv, float* dego, int n) {
  __shared__ int wsum[16];
  const int t = threadIdx.x;
  const int dir = blockIdx.x;
  int* cnt = dir ? cnt_s : cnt_d;
  int* off = dir ? off_s : off_d;
  const int PT = (n + 1023) >> 10;          // 8 for n=8000
  const int i0 = t * PT;
  int c[8];
  int tot = 0;
  #pragma unroll
  for (int j = 0; j < 8; ++j) {
    const int i = i0 + j;
    c[j] = (j < PT && i < n) ? cnt[i] : 0;
    tot += c[j];
  }
  // wave-inclusive scan of per-thread totals
  const int lane = t & 63, w = t >> 6;
  int v = tot;
  #pragma unroll
  for (int o = 1; o < 64; o <<= 1) {
    int u = __shfl_up(v, o, 64);
    if (lane >= o) v += u;
  }
  if (lane == 63) wsum[w] = v;
  __syncthreads();
  int wbase = 0;
  #pragma unroll
  for (int k = 0; k < 16; ++k) wbase += (k < w) ? wsum[k] : 0;
  int excl = wbase + v - tot;               // exclusive prefix for this thread
  #pragma unroll
  for (int j = 0; j < 8; ++j) {
    const int i = i0 + j;
    if (j < PT && i < n) {
      off[i] = excl;
      if (dir == 0) dinv[i] = rsqrtf((float)c[j] + 1.0f);
      else          dego[i] = (float)c[j];
      cnt[i] = 0;                            // fill cursor
      excl += c[j];
    }
  }
  if (t == 0) {
    int s = 0;
    #pragma unroll
    for (int k = 0; k < 16; ++k) s += wsum[k];
    off[n] = s;
  }
}

// ---- fused: layer-1 GEMM with dinv prescale (blocks < NT) + CSR fill ------
// Hbs[i] = dinv[i] * (X @ W1)[i]  (bf16)
__global__ __launch_bounds__(256) void k_gemm1_fill(const float* __restrict__ X,
                                                    const float* __restrict__ W,
                                                    const float* __restrict__ dinv,
                                                    unsigned short* __restrict__ Hb,
                                                    const int* __restrict__ ei, int E,
                                                    const int* __restrict__ off_d,
                                                    const int* __restrict__ off_s,
                                                    int* cnt_d, int* cnt_s,
                                                    int* idx_d, int* idx_s, int NT) {
  __shared__ float Ws[64 * DH];
  __shared__ float xs[16 * 128];
  const int t = threadIdx.x;
  if ((int)blockIdx.x < NT) {
    const int row0 = blockIdx.x * 16;
    const float4* xg = (const float4*)(X + row0 * 128);
    float4* xs4 = (float4*)xs;
    xs4[t] = xg[t];
    xs4[t + 256] = xg[t + 256];
    const int c = t & 127, rg = t >> 7;   // RPT = 8
    float acc[8];
    #pragma unroll
    for (int r = 0; r < 8; ++r) acc[r] = 0.f;
    for (int kt = 0; kt < 2; ++kt) {
      __syncthreads();
      for (int i = t; i < 64 * DH; i += 256) Ws[i] = W[kt * 64 * DH + i];
      __syncthreads();
      for (int k = 0; k < 64; ++k) {
        float wv = Ws[k * DH + c];
        #pragma unroll
        for (int r = 0; r < 8; ++r)
          acc[r] += xs[(rg * 8 + r) * 128 + kt * 64 + k] * wv;
      }
    }
    #pragma unroll
    for (int r = 0; r < 8; ++r) {
      const int row = row0 + rg * 8 + r;
      Hb[row * DH + c] = f2bf(dinv[row] * acc[r]);
    }
  } else {
    const int nb = gridDim.x - NT;
    for (int e = (blockIdx.x - NT) * 256 + t; e < E; e += nb * 256) {
      int s = ei[e], d = ei[E + e];
      int p = atomicAdd(&cnt_d[d], 1);
      idx_d[off_d[d] + p] = s;
      int q = atomicAdd(&cnt_s[s], 1);
      idx_s[off_s[s] + q] = d;
    }
  }
}

// ------- conv aggregate (prescaled rows): 16 lanes/node, uint4/lane --------
// G_i = b + dinv_i * (Hbs[i] + sum_{s in in(i)} Hbs[s])
__global__ __launch_bounds__(256) void k_conv_agg(const unsigned short* __restrict__ Hb,
                                                  const float* __restrict__ dinv,
                                                  const float* __restrict__ b,
                                                  const int* __restrict__ off_d,
                                                  const int* __restrict__ idx_d,
                                                  float* __restrict__ G,
                                                  unsigned short* __restrict__ Gb,
                                                  float* __restrict__ sq) {
  const int lane = threadIdx.x & 15;
  const int i = blockIdx.x * 16 + (threadIdx.x >> 4);
  const uint4* Hv = (const uint4*)Hb;
  const float di = dinv[i];
  float acc[8];
  dec8(Hv[i * 16 + lane], acc);              // self row (already dinv-scaled)
  int o = off_d[i];
  const int oe = off_d[i + 1];
  for (; o + 8 <= oe; o += 8) {
    int s[8]; uint4 r[8];
    #pragma unroll
    for (int j = 0; j < 8; ++j) s[j] = idx_d[o + j];
    #pragma unroll
    for (int j = 0; j < 8; ++j) r[j] = Hv[s[j] * 16 + lane];
    #pragma unroll
    for (int j = 0; j < 8; ++j) {
      float t8[8]; dec8(r[j], t8);
      #pragma unroll
      for (int k = 0; k < 8; ++k) acc[k] += t8[k];
    }
  }
  for (; o < oe; ++o) {
    int s = idx_d[o];
    float t8[8]; dec8(Hv[s * 16 + lane], t8);
    #pragma unroll
    for (int k = 0; k < 8; ++k) acc[k] += t8[k];
  }
  const float4 b0 = ((const float4*)b)[lane * 2];
  const float4 b1 = ((const float4*)b)[lane * 2 + 1];
  float gi[8];
  gi[0] = fmaf(di, acc[0], b0.x); gi[1] = fmaf(di, acc[1], b0.y);
  gi[2] = fmaf(di, acc[2], b0.z); gi[3] = fmaf(di, acc[3], b0.w);
  gi[4] = fmaf(di, acc[4], b1.x); gi[5] = fmaf(di, acc[5], b1.y);
  gi[6] = fmaf(di, acc[6], b1.z); gi[7] = fmaf(di, acc[7], b1.w);
  ((float4*)G)[i * 32 + lane * 2]     = make_float4(gi[0], gi[1], gi[2], gi[3]);
  ((float4*)G)[i * 32 + lane * 2 + 1] = make_float4(gi[4], gi[5], gi[6], gi[7]);
  uint4 gp;
  gp.x = pack2(gi[0], gi[1]); gp.y = pack2(gi[2], gi[3]);
  gp.z = pack2(gi[4], gi[5]); gp.w = pack2(gi[6], gi[7]);
  ((uint4*)Gb)[i * 16 + lane] = gp;
  float s2 = 0.f;
  #pragma unroll
  for (int k = 0; k < 8; ++k) s2 += gi[k] * gi[k];
  s2 = grp_sum16(s2);
  if (lane == 0) sq[i] = s2;
}

// ------- Ax = A@G (CSR_src), Asq, En; block-reduced atomicMax(En) ----------
__global__ __launch_bounds__(256) void k_ax_en(const float* __restrict__ G,
                                               const unsigned short* __restrict__ Gb,
                                               const float* __restrict__ sq,
                                               const float* __restrict__ dego,
                                               const int* __restrict__ off_s,
                                               const int* __restrict__ idx_s,
                                               float* __restrict__ Ax,
                                               float* __restrict__ En,
                                               float* __restrict__ gmax) {
  __shared__ float smax[16];
  const int lane = threadIdx.x & 15;
  const int i = blockIdx.x * 16 + (threadIdx.x >> 4);
  const uint4* Gv = (const uint4*)Gb;
  float axf[8];
  #pragma unroll
  for (int k = 0; k < 8; ++k) axf[k] = 0.f;
  float asq = 0.f;
  int o = off_s[i];
  const int oe = off_s[i + 1];
  for (; o + 8 <= oe; o += 8) {
    int s[8]; float qv[8]; uint4 r[8];
    #pragma unroll
    for (int j = 0; j < 8; ++j) s[j] = idx_s[o + j];
    #pragma unroll
    for (int j = 0; j < 8; ++j) { r[j] = Gv[s[j] * 16 + lane]; qv[j] = sq[s[j]]; }
    #pragma unroll
    for (int j = 0; j < 8; ++j) {
      float t8[8]; dec8(r[j], t8);
      asq += qv[j];
      #pragma unroll
      for (int k = 0; k < 8; ++k) axf[k] += t8[k];
    }
  }
  for (; o < oe; ++o) {
    int s = idx_s[o];
    float t8[8]; dec8(Gv[s * 16 + lane], t8);
    asq += sq[s];
    #pragma unroll
    for (int k = 0; k < 8; ++k) axf[k] += t8[k];
  }
  ((float4*)Ax)[i * 32 + lane * 2]     = make_float4(axf[0], axf[1], axf[2], axf[3]);
  ((float4*)Ax)[i * 32 + lane * 2 + 1] = make_float4(axf[4], axf[5], axf[6], axf[7]);
  const float4 g0 = ((const float4*)G)[i * 32 + lane * 2];
  const float4 g1 = ((const float4*)G)[i * 32 + lane * 2 + 1];
  float dot = g0.x * axf[0] + g0.y * axf[1] + g0.z * axf[2] + g0.w * axf[3]
            + g1.x * axf[4] + g1.y * axf[5] + g1.z * axf[6] + g1.w * axf[7];
  dot = grp_sum16(dot);
  if (lane == 0) {
    float en = 0.5f * (dego[i] * sq[i] + asq - 2.f * dot);
    En[i] = en;
    smax[threadIdx.x >> 4] = en;
  }
  __syncthreads();
  if (threadIdx.x == 0) {
    float m = smax[0];
    #pragma unroll
    for (int k = 1; k < 16; ++k) m = fmaxf(m, smax[k]);
    atomicMax((int*)gmax, __float_as_int(m));   // En >= 0: int-max == float-max
  }
}

// ------- fused: softmax stats + combine + relu + LN + GEMM tile ------------
// Block = 16 nodes (16 lanes x 8 feats each) = one 16-row GEMM tile.
// Global max(En) precomputed by k_ax_en (gmaxp). W staged in LDS (occupancy
// is block-limited at 500 blocks / 256 CU, so L2-latency in the GEMM inner
// loop is NOT hidden without staging -- round-4 lesson).
template <int DOUT>
__global__ __launch_bounds__(256) void k_combine_gemm(const float* __restrict__ G,
                                                      const unsigned short* __restrict__ Gb,
                                                      const float* __restrict__ Ax,
                                                      const float* __restrict__ En,
                                                      const float* __restrict__ dego,
                                                      const float* __restrict__ dinv,
                                                      const int* __restrict__ off_d,
                                                      const int* __restrict__ idx_d,
                                                      const float* __restrict__ gamma,
                                                      const float* __restrict__ beta,
                                                      const float* __restrict__ W,
                                                      unsigned short* __restrict__ Hb,
                                                      const float* __restrict__ gmaxp,
                                                      int n) {
  __shared__ float Ws[64 * DOUT];
  __shared__ float xs[16 * 128];
  __shared__ float s4[4];
  const int t = threadIdx.x;
  // ---- softmax statistics prologue (max already global via k_ax_en) ----
  const float m = gmaxp[0];
  const float invden = -1.0f / ((m + 1e-12f) * TEMP_);   // li = En*invden
  float se = 0.f, sl = 0.f;
  const float4* En4 = (const float4*)En;
  for (int k = t; k < (n >> 2); k += 256) {
    float4 e4 = En4[k];
    float l0 = e4.x * invden, l1 = e4.y * invden;
    float l2 = e4.z * invden, l3 = e4.w * invden;
    float e0 = __expf(l0), e1 = __expf(l1), e2 = __expf(l2), e3 = __expf(l3);
    se += (e0 + e1) + (e2 + e3);
    sl += (e0 * l0 + e1 * l1) + (e2 * l2 + e3 * l3);
  }
  se = blkred(se, s4);
  sl = blkred(sl, s4);
  const float logZ = __logf(se);
  const float S = logZ - sl / se;
  const float cmul = (1.0f / se) * (1.0f / TEMP_);
  const float cadd = S - logZ;

  // ---- per-node combine + LN ----
  const int lane = t & 15;
  const int i = blockIdx.x * 16 + (t >> 4);
  const uint4* Gv = (const uint4*)Gb;
  const float4 g0 = ((const float4*)G)[i * 32 + lane * 2];
  const float4 g1 = ((const float4*)G)[i * 32 + lane * 2 + 1];
  const float gi[8] = { g0.x, g0.y, g0.z, g0.w, g1.x, g1.y, g1.z, g1.w };
  float tf[8];
  #pragma unroll
  for (int k = 0; k < 8; ++k) tf[k] = 0.f;
  float atc = 0.f;
  int o = off_d[i];
  const int oe = off_d[i + 1];
  for (; o + 8 <= oe; o += 8) {
    int s[8]; float ev[8]; uint4 r[8];
    #pragma unroll
    for (int j = 0; j < 8; ++j) s[j] = idx_d[o + j];
    #pragma unroll
    for (int j = 0; j < 8; ++j) { r[j] = Gv[s[j] * 16 + lane]; ev[j] = En[s[j]]; }
    #pragma unroll
    for (int j = 0; j < 8; ++j) {
      float ls = ev[j] * invden;
      float cs = __expf(ls) * cmul * (ls + cadd);
      atc += cs;
      float t8[8]; dec8(r[j], t8);
      #pragma unroll
      for (int k = 0; k < 8; ++k) tf[k] = fmaf(cs, t8[k], tf[k]);
    }
  }
  for (; o < oe; ++o) {
    int s = idx_d[o];
    float ls = En[s] * invden;
    float cs = __expf(ls) * cmul * (ls + cadd);
    atc += cs;
    float t8[8]; dec8(Gv[s * 16 + lane], t8);
    #pragma unroll
    for (int k = 0; k < 8; ++k) tf[k] = fmaf(cs, t8[k], tf[k]);
  }
  const float li_i = En[i] * invden;
  const float ci = __expf(li_i) * cmul * (li_i + cadd);
  const float dg = dego[i];
  const float4 a0 = ((const float4*)Ax)[i * 32 + lane * 2];
  const float4 a1 = ((const float4*)Ax)[i * 32 + lane * 2 + 1];
  const float axi[8] = { a0.x, a0.y, a0.z, a0.w, a1.x, a1.y, a1.z, a1.w };
  float v[8];
  float ssum = 0.f;
  #pragma unroll
  for (int k = 0; k < 8; ++k) {
    v[k] = fmaxf(gi[k] + ci * (dg * gi[k] - axi[k]) + atc * gi[k] - tf[k], 0.f);
    ssum += v[k];
  }
  float mu = grp_sum16(ssum) * (1.f / 128.f);
  float vsum = 0.f;
  #pragma unroll
  for (int k = 0; k < 8; ++k) {
    v[k] -= mu;
    vsum += v[k] * v[k];
  }
  float var = grp_sum16(vsum) * (1.f / 128.f);
  float rs = rsqrtf(var + LN_EPS_);
  const float4 ga0 = ((const float4*)gamma)[lane * 2];
  const float4 ga1 = ((const float4*)gamma)[lane * 2 + 1];
  const float4 be0 = ((const float4*)beta)[lane * 2];
  const float4 be1 = ((const float4*)beta)[lane * 2 + 1];
  float4 o0, o1;
  o0.x = fmaf(v[0] * rs, ga0.x, be0.x); o0.y = fmaf(v[1] * rs, ga0.y, be0.y);
  o0.z = fmaf(v[2] * rs, ga0.z, be0.z); o0.w = fmaf(v[3] * rs, ga0.w, be0.w);
  o1.x = fmaf(v[4] * rs, ga1.x, be1.x); o1.y = fmaf(v[5] * rs, ga1.y, be1.y);
  o1.z = fmaf(v[6] * rs, ga1.z, be1.z); o1.w = fmaf(v[7] * rs, ga1.w, be1.w);

  // ---- stage LN rows to LDS, then GEMM this 16-row tile ----
  float* xrow = xs + (t >> 4) * 128 + lane * 8;
  ((float4*)xrow)[0] = o0;
  ((float4*)xrow)[1] = o1;

  const int row0 = blockIdx.x * 16;
  constexpr int RPT = (16 * DOUT) / 256;
  const int c = t % DOUT;
  const int rg = t / DOUT;
  float acc[RPT];
  #pragma unroll
  for (int r = 0; r < RPT; ++r) acc[r] = 0.f;
  for (int kt = 0; kt < 2; ++kt) {
    if (kt) __syncthreads();
    for (int idx = t; idx < 64 * DOUT; idx += 256) Ws[idx] = W[kt * 64 * DOUT + idx];
    __syncthreads();
    for (int k = 0; k < 64; ++k) {
      float wv = Ws[k * DOUT + c];
      #pragma unroll
      for (int r = 0; r < RPT; ++r)
        acc[r] += xs[(rg * RPT + r) * 128 + kt * 64 + k] * wv;
    }
  }
  #pragma unroll
  for (int r = 0; r < RPT; ++r) {
    const int row = row0 + rg * RPT + r;
    Hb[row * DOUT + c] = f2bf(dinv[row] * acc[r]);   // prescaled output
  }
}

// ------- final conv aggregate (prescaled, DOUT=64): 8 lanes/node -----------
__global__ __launch_bounds__(256) void k_final_agg(const unsigned short* __restrict__ Hb,
                                                   const float* __restrict__ dinv,
                                                   const float* __restrict__ bout,
                                                   const int* __restrict__ off_d,
                                                   const int* __restrict__ idx_d,
                                                   float* __restrict__ out) {
  const int lane = threadIdx.x & 7;
  const int i = blockIdx.x * 32 + (threadIdx.x >> 3);
  const uint4* Hv = (const uint4*)Hb;
  const float di = dinv[i];
  float acc[8];
  dec8(Hv[i * 8 + lane], acc);               // self row (already dinv-scaled)
  int o = off_d[i];
  const int oe = off_d[i + 1];
  for (; o + 8 <= oe; o += 8) {
    int s[8]; uint4 r[8];
    #pragma unroll
    for (int j = 0; j < 8; ++j) s[j] = idx_d[o + j];
    #pragma unroll
    for (int j = 0; j < 8; ++j) r[j] = Hv[s[j] * 8 + lane];
    #pragma unroll
    for (int j = 0; j < 8; ++j) {
      float t8[8]; dec8(r[j], t8);
      #pragma unroll
      for (int k = 0; k < 8; ++k) acc[k] += t8[k];
    }
  }
  for (; o < oe; ++o) {
    int s = idx_d[o];
    float t8[8]; dec8(Hv[s * 8 + lane], t8);
    #pragma unroll
    for (int k = 0; k < 8; ++k) acc[k] += t8[k];
  }
  const float4 b0 = ((const float4*)bout)[lane * 2];
  const float4 b1 = ((const float4*)bout)[lane * 2 + 1];
  float4 r0, r1;
  r0.x = fmaf(di, acc[0], b0.x); r0.y = fmaf(di, acc[1], b0.y);
  r0.z = fmaf(di, acc[2], b0.z); r0.w = fmaf(di, acc[3], b0.w);
  r1.x = fmaf(di, acc[4], b1.x); r1.y = fmaf(di, acc[5], b1.y);
  r1.z = fmaf(di, acc[6], b1.z); r1.w = fmaf(di, acc[7], b1.w);
  ((float4*)out)[i * 16 + lane * 2]     = r0;
  ((float4*)out)[i * 16 + lane * 2 + 1] = r1;
}

extern "C" void kernel_launch(void* const* d_in, const int* in_sizes, int n_in,
                              void* d_out, int out_size, void* d_ws, size_t ws_size,
                              hipStream_t stream) {
  const float* x    = (const float*)d_in[0];
  const int*   ei   = (const int*)d_in[1];
  const float* W1   = (const float*)d_in[2];
  const float* b1   = (const float*)d_in[3];
  const float* W2   = (const float*)d_in[4];
  const float* b2   = (const float*)d_in[5];
  const float* Wout = (const float*)d_in[6];
  const float* bout = (const float*)d_in[7];
  const float* gam  = (const float*)d_in[8];
  const float* bet  = (const float*)d_in[9];
  float* out = (float*)d_out;

  const int N = in_sizes[0] / DH;   // 8000
  const int E = in_sizes[1] / 2;    // 256000

  float* ws = (float*)d_ws;
  float* G  = ws;   ws += N * DH;
  float* Ax = ws;   ws += N * DH;
  float* sq = ws;   ws += N;
  float* En = ws;   ws += N;
  float* dinv = ws; ws += N;
  float* dego = ws; ws += N;
  unsigned short* Hb = (unsigned short*)ws; ws += N * DH / 2;   // bf16 N x 128
  unsigned short* Gb = (unsigned short*)ws; ws += N * DH / 2;   // bf16 N x 128
  int* cnt_d  = (int*)ws; ws += N;
  int* cnt_s  = (int*)ws; ws += N;
  float* gmax = (float*)ws; ws += 2;   // [0]=layer0 max, [1]=layer1 max
  int* off_d  = (int*)ws; ws += N + 4;
  int* off_s  = (int*)ws; ws += N + 4;
  int* idx_d  = (int*)ws; ws += E;
  int* idx_s  = (int*)ws; ws += E;

  const int NT = N / 16;            // 500 gemm tile blocks

  // zero cnt_d, cnt_s, gmax (contiguous)
  hipMemsetAsync(cnt_d, 0, (size_t)(2 * N + 2) * sizeof(int), stream);
  k_hist<<<256, 256, 0, stream>>>(ei, E, cnt_d, cnt_s);
  k_scan<<<2, 1024, 0, stream>>>(cnt_d, cnt_s, off_d, off_s, dinv, dego, N);
  k_gemm1_fill<<<NT + (E + 255) / 256, 256, 0, stream>>>(x, W1, dinv, Hb, ei, E,
                                                         off_d, off_s, cnt_d, cnt_s,
                                                         idx_d, idx_s, NT);

  // layer 0
  k_conv_agg<<<N / 16, 256, 0, stream>>>(Hb, dinv, b1, off_d, idx_d, G, Gb, sq);
  k_ax_en<<<N / 16, 256, 0, stream>>>(G, Gb, sq, dego, off_s, idx_s, Ax, En, gmax);
  k_combine_gemm<128><<<N / 16, 256, 0, stream>>>(G, Gb, Ax, En, dego, dinv, off_d,
                                                  idx_d, gam, bet, W2, Hb, gmax, N);
  // layer 1
  k_conv_agg<<<N / 16, 256, 0, stream>>>(Hb, dinv, b2, off_d, idx_d, G, Gb, sq);
  k_ax_en<<<N / 16, 256, 0, stream>>>(G, Gb, sq, dego, off_s, idx_s, Ax, En, gmax + 1);
  k_combine_gemm<64><<<N / 16, 256, 0, stream>>>(G, Gb, Ax, En, dego, dinv, off_d,
                                                 idx_d, gam, bet, Wout, Hb, gmax + 1, N);
  k_final_agg<<<N / 32, 256, 0, stream>>>(Hb, dinv, bout, off_d, idx_d, out);
}